// Round 2
// baseline (387.098 us; speedup 1.0000x reference)
//
#include <hip/hip_runtime.h>
#include <math.h>

#define HDIM 128

// ---------------------------------------------------------------- utilities
__device__ __forceinline__ int load_idx(const void* ei, long long E, int which,
                                        long long e, int is64) {
    if (is64) {
        const long long* p = (const long long*)ei;
        return (int)p[(long long)which * E + e];
    } else {
        const int* p = (const int*)ei;
        return p[(long long)which * E + e];
    }
}

// Clamp any value to a guaranteed-finite float (nan -> -3e38).
__device__ __forceinline__ float fin(float x) {
    if (!(x > -3.0e38f)) return -3.0e38f;  // catches nan and -inf
    if (x > 3.0e38f) return 3.0e38f;
    return x;
}

// Detect int64 vs int32 edge_index: sample high dwords of first 4096 slots.
__global__ void detect64_kernel(const unsigned* u, long long n_dwords,
                                int* flag) {
    __shared__ int any;
    if (threadIdx.x == 0) any = 0;
    __syncthreads();
    long long slots = n_dwords / 2;
    long long cap = slots < 4096 ? slots : 4096;
    for (long long i = threadIdx.x; i < cap; i += blockDim.x)
        if (u[2 * i + 1] != 0u) any = 1;  // benign race, monotonic
    __syncthreads();
    if (threadIdx.x == 0) *flag = any ? 0 : 1;
}

__global__ void zero_cnt_kernel(int* cnt, int n) {
    int i = blockIdx.x * blockDim.x + threadIdx.x;
    int stride = gridDim.x * blockDim.x;
    for (; i < n; i += stride) cnt[i] = 0;
}

__global__ void count_edges_kernel(const void* ei, const int* flag64, int* cnt,
                                   long long E, int n) {
    long long e = (long long)blockIdx.x * blockDim.x + threadIdx.x;
    long long stride = (long long)gridDim.x * blockDim.x;
    int is64 = *flag64;
    for (; e < E; e += stride) {
        int d = load_idx(ei, E, 1, e, is64);
        if ((unsigned)d < (unsigned)n) atomicAdd(&cnt[d], 1);
    }
}

// Single-block exclusive scan -> rowstart, wcur; also dinv = rsqrt(cnt+1).
__global__ __launch_bounds__(1024) void scan_csr_kernel(
        const int* __restrict__ cnt, int* __restrict__ rowstart,
        int* __restrict__ wcur, float* __restrict__ dinv, int n) {
    __shared__ int sd[1024];
    __shared__ int s_carry;
    int t = threadIdx.x;
    if (t == 0) s_carry = 0;
    __syncthreads();
    int nloop = (n + 1023) / 1024;
    for (int bi = 0; bi < nloop; ++bi) {
        int i = bi * 1024 + t;
        int v = (i < n) ? cnt[i] : 0;
        sd[t] = v;
        __syncthreads();
        for (int off = 1; off < 1024; off <<= 1) {
            int add = (t >= off) ? sd[t - off] : 0;
            __syncthreads();
            sd[t] += add;
            __syncthreads();
        }
        int carry = s_carry;
        int incl = sd[t];
        if (i < n) {
            int excl = carry + incl - v;
            rowstart[i] = excl;
            wcur[i] = excl;
            dinv[i] = rsqrtf((float)(v + 1));
        }
        __syncthreads();
        if (t == 1023) s_carry = carry + incl;
        __syncthreads();
    }
    if (t == 0) rowstart[n] = s_carry;
}

__global__ void fill_elist_kernel(const void* ei, const int* flag64, int* wcur,
                                  int* elist, long long E, int n) {
    long long e = (long long)blockIdx.x * blockDim.x + threadIdx.x;
    long long stride = (long long)gridDim.x * blockDim.x;
    int is64 = *flag64;
    for (; e < E; e += stride) {
        int s = load_idx(ei, E, 0, e, is64);
        int d = load_idx(ei, E, 1, e, is64);
        if ((unsigned)d >= (unsigned)n) continue;      // matches count guard
        if ((unsigned)s >= (unsigned)n) s = d;         // safe fallback
        int pos = atomicAdd(&wcur[d], 1);
        if (pos >= 0 && pos < (int)E) elist[pos] = s;  // never scribble OOB
    }
}

// ------------------------------------------------------------------- GEMM
// Y[r][c] = dinv[r] * sum_k X[r][k] * W[k][c]     (N x 128) @ (128 x 128)
#define GFMA(cc, xs)                                                           \
    cc.x = fmaf(xs, wv.x, cc.x);                                               \
    cc.y = fmaf(xs, wv.y, cc.y);                                               \
    cc.z = fmaf(xs, wv.z, cc.z);                                               \
    cc.w = fmaf(xs, wv.w, cc.w);

#define GSTORE(cc, j)                                                          \
    {                                                                          \
        int gr = R0 + row0 + (j);                                              \
        if (gr < n) {                                                          \
            float dv = dinv[gr];                                               \
            float4 o;                                                          \
            o.x = dv * cc.x; o.y = dv * cc.y; o.z = dv * cc.z; o.w = dv * cc.w;\
            *(float4*)(Y + (size_t)gr * HDIM + col0) = o;                      \
        }                                                                      \
    }

__global__ __launch_bounds__(256) void gemm_scaled_kernel(
        const float* __restrict__ X, const float* __restrict__ Wg,
        const float* __restrict__ dinv, float* __restrict__ Y, int n) {
    __shared__ float xT[HDIM][32];
    int R0 = blockIdx.x * 32;
    int t = threadIdx.x;
    {   // stage x tile transposed: xT[k][r] = X[R0+r][k]
        int r = t & 31, kq8 = t >> 5;
        const float* xr = X + (size_t)(R0 + r) * HDIM;
        bool ok = (R0 + r) < n;
#pragma unroll
        for (int p = 0; p < 4; ++p) {
            int kq = kq8 + p * 8;
            float4 xv = ok ? ((const float4*)xr)[kq] : make_float4(0.f, 0.f, 0.f, 0.f);
            xT[kq * 4 + 0][r] = xv.x;
            xT[kq * 4 + 1][r] = xv.y;
            xT[kq * 4 + 2][r] = xv.z;
            xT[kq * 4 + 3][r] = xv.w;
        }
    }
    __syncthreads();
    int w = t >> 6, lane = t & 63;
    int rg = w >> 1, cg = w & 1;
    int rq = lane >> 4, cq = lane & 15;
    int row0 = rg * 16 + rq * 4;
    int col0 = cg * 64 + cq * 4;
    const float* Wp = Wg + col0;
    float4 c0 = make_float4(0.f, 0.f, 0.f, 0.f), c1 = c0, c2 = c0, c3 = c0;
#pragma unroll 4
    for (int k = 0; k < HDIM; ++k) {
        float4 wv = *(const float4*)(Wp + (size_t)k * HDIM);
        float4 xv = *(const float4*)(&xT[k][row0]);
        GFMA(c0, xv.x);
        GFMA(c1, xv.y);
        GFMA(c2, xv.z);
        GFMA(c3, xv.w);
    }
    GSTORE(c0, 0);
    GSTORE(c1, 1);
    GSTORE(c2, 2);
    GSTORE(c3, 3);
}

// -------------------------------------------------------------------- pull
// H[v] = relu(bias + dinv[v] * (Y[v] + sum_{incoming e} Y[src_e]))
__global__ __launch_bounds__(256) void pull_relu_kernel(
        const float* __restrict__ Y, const int* __restrict__ rowstart,
        const int* __restrict__ elist, const float* __restrict__ dinv,
        const float* __restrict__ bias, float* __restrict__ H, int n) {
    int gw = (int)((blockIdx.x * blockDim.x + threadIdx.x) >> 6);
    int lane = threadIdx.x & 63;
    if (gw >= n) return;
    int v = gw;
    float2 a0 = ((const float2*)(Y + (size_t)v * HDIM))[lane];  // self loop
    float2 a1 = make_float2(0.f, 0.f), a2 = a1, a3 = a1;
    int i = rowstart[v], e = rowstart[v + 1];
    for (; i + 4 <= e; i += 4) {
        int sA = elist[i], sB = elist[i + 1], sC = elist[i + 2], sD = elist[i + 3];
        if ((unsigned)sA >= (unsigned)n) sA = v;
        if ((unsigned)sB >= (unsigned)n) sB = v;
        if ((unsigned)sC >= (unsigned)n) sC = v;
        if ((unsigned)sD >= (unsigned)n) sD = v;
        float2 mA = ((const float2*)(Y + (size_t)sA * HDIM))[lane];
        float2 mB = ((const float2*)(Y + (size_t)sB * HDIM))[lane];
        float2 mC = ((const float2*)(Y + (size_t)sC * HDIM))[lane];
        float2 mD = ((const float2*)(Y + (size_t)sD * HDIM))[lane];
        a0.x += mA.x; a0.y += mA.y;
        a1.x += mB.x; a1.y += mB.y;
        a2.x += mC.x; a2.y += mC.y;
        a3.x += mD.x; a3.y += mD.y;
    }
    for (; i < e; ++i) {
        int s = elist[i];
        if ((unsigned)s >= (unsigned)n) s = v;
        float2 m = ((const float2*)(Y + (size_t)s * HDIM))[lane];
        a0.x += m.x; a0.y += m.y;
    }
    float dv = dinv[v];
    float2 b = ((const float2*)bias)[lane];
    float hx = fmaxf(fmaf(dv, a0.x + a1.x + a2.x + a3.x, b.x), 0.f);
    float hy = fmaxf(fmaf(dv, a0.y + a1.y + a2.y + a3.y, b.y), 0.f);
    ((float2*)(H + (size_t)v * HDIM))[lane] = make_float2(hx, hy);
}

// ------------------------------------------------------------------- heads
#define SENT (-3.0e38f)

#define HEAD_STEP(hk, k)                                                       \
    {                                                                          \
        float2 wd = ((const float2*)Wdet)[k];                                  \
        d0 = fmaf(hk, wd.x, d0); d1 = fmaf(hk, wd.y, d1);                      \
        float2 wu = ((const float2*)Wund)[k];                                  \
        u0 = fmaf(hk, wu.x, u0); u1 = fmaf(hk, wu.y, u1);                      \
        float4 wr = ((const float4*)Wroot)[k];                                 \
        r0 = fmaf(hk, wr.x, r0); r1 = fmaf(hk, wr.y, r1);                      \
        r2 = fmaf(hk, wr.z, r2); r3 = fmaf(hk, wr.w, r3);                      \
    }

__global__ __launch_bounds__(256) void heads_kernel(
        const float* __restrict__ Hh, const float* __restrict__ Wdet,
        const float* __restrict__ bdet, const float* __restrict__ Wund,
        const float* __restrict__ bund, const float* __restrict__ Wroot,
        const float* __restrict__ broot, float* __restrict__ out, int n) {
    int nid = blockIdx.x * blockDim.x + threadIdx.x;
    if (nid >= n) return;
    const float4* hp = (const float4*)(Hh + (size_t)nid * HDIM);
    float d0 = 0.f, d1 = 0.f, u0 = 0.f, u1 = 0.f;
    float r0 = 0.f, r1 = 0.f, r2 = 0.f, r3 = 0.f;
#pragma unroll 8
    for (int kq = 0; kq < 32; ++kq) {
        float4 hv = hp[kq];
        HEAD_STEP(hv.x, kq * 4 + 0);
        HEAD_STEP(hv.y, kq * 4 + 1);
        HEAD_STEP(hv.z, kq * 4 + 2);
        HEAD_STEP(hv.w, kq * 4 + 3);
    }
    d0 += bdet[0]; d1 += bdet[1];
    u0 += bund[0]; u1 += bund[1];
    r0 += broot[0]; r1 += broot[1]; r2 += broot[2]; r3 += broot[3];

    // det log_softmax
    float m = fmaxf(d0, d1);
    float lse = m + logf(expf(d0 - m) + expf(d1 - m));
    out[(size_t)nid * 2 + 0] = fin(d0 - lse);
    out[(size_t)nid * 2 + 1] = fin(d1 - lse);

    float* ro = out + 2 * (size_t)n + (size_t)nid * 5;
    if (d1 > d0) {  // argmax == 1 (strict: tie -> index 0 -> false)
        float mm = fmaxf(fmaxf(r0, r1), fmaxf(r2, r3));
        float l2 = mm + logf(expf(r0 - mm) + expf(r1 - mm) + expf(r2 - mm) +
                             expf(r3 - mm));
        ro[0] = SENT;  // reference: -inf (finite sentinel avoids inf-inf=nan)
        ro[1] = fin(r0 - l2);
        ro[2] = fin(r1 - l2);
        ro[3] = fin(r2 - l2);
        ro[4] = fin(r3 - l2);
    } else {
        float mm = fmaxf(u0, u1);
        float l2 = mm + logf(expf(u0 - mm) + expf(u1 - mm));
        ro[0] = fin(u0 - l2);
        ro[1] = fin(u1 - l2);
        ro[2] = SENT;
        ro[3] = SENT;
        ro[4] = SENT;
    }
}

__global__ void ws_too_small_kernel(float* out, int n) {
    int i = blockIdx.x * blockDim.x + threadIdx.x;
    if (i < n) out[i] = -12345.0f;  // sentinel: workspace was insufficient
}

// ----------------------------------------------------------------- launch
extern "C" void kernel_launch(void* const* d_in, const int* in_sizes, int n_in,
                              void* d_out, int out_size, void* d_ws,
                              size_t ws_size, hipStream_t stream) {
    const float* x     = (const float*)d_in[0];
    const void*  ei    = d_in[1];
    const float* W1    = (const float*)d_in[2];
    const float* b1    = (const float*)d_in[3];
    const float* W2    = (const float*)d_in[4];
    const float* b2    = (const float*)d_in[5];
    const float* Wdet  = (const float*)d_in[6];
    const float* bdet  = (const float*)d_in[7];
    const float* Wund  = (const float*)d_in[8];
    const float* bund  = (const float*)d_in[9];
    const float* Wroot = (const float*)d_in[10];
    const float* broot = (const float*)d_in[11];
    int N = in_sizes[0] / HDIM;       // 50000
    long long E = in_sizes[1] / 2;    // 800000
    float* out = (float*)d_out;

    // workspace carve (256B aligned)
    size_t off = 0;
    auto carve = [&](size_t bytes) -> void* {
        void* p = (char*)d_ws + off;
        off += (bytes + 255) & ~(size_t)255;
        return p;
    };
    float* A        = (float*)carve((size_t)N * HDIM * 4);
    float* B        = (float*)carve((size_t)N * HDIM * 4);
    float* dinv     = (float*)carve((size_t)N * 4);
    int*   cnt      = (int*)carve((size_t)N * 4);
    int*   rowstart = (int*)carve((size_t)(N + 1) * 4);
    int*   wcur     = (int*)carve((size_t)N * 4);
    int*   elist    = (int*)carve((size_t)E * 4);
    int*   flag64   = (int*)carve(256);

    if (off > ws_size) {
        ws_too_small_kernel<<<(out_size + 255) / 256, 256, 0, stream>>>(out, out_size);
        return;
    }

    // CSR build
    detect64_kernel<<<1, 256, 0, stream>>>((const unsigned*)ei,
                                           (long long)in_sizes[1], flag64);
    zero_cnt_kernel<<<256, 256, 0, stream>>>(cnt, N);
    count_edges_kernel<<<2048, 256, 0, stream>>>(ei, flag64, cnt, E, N);
    scan_csr_kernel<<<1, 1024, 0, stream>>>(cnt, rowstart, wcur, dinv, N);
    fill_elist_kernel<<<2048, 256, 0, stream>>>(ei, flag64, wcur, elist, E, N);

    int gemm_grid = (N + 31) / 32;
    int pull_grid = (N + 3) / 4;      // 4 waves (nodes) per 256-thread block
    int head_grid = (N + 255) / 256;

    // layer 1: A = dinv * (x @ W1);  B = relu(b1 + dinv*(A_self + gather))
    gemm_scaled_kernel<<<gemm_grid, 256, 0, stream>>>(x, W1, dinv, A, N);
    pull_relu_kernel<<<pull_grid, 256, 0, stream>>>(A, rowstart, elist, dinv, b1, B, N);
    // layer 2: A = dinv * (B @ W2);  B = relu(b2 + dinv*(A_self + gather))
    gemm_scaled_kernel<<<gemm_grid, 256, 0, stream>>>(B, W2, dinv, A, N);
    pull_relu_kernel<<<pull_grid, 256, 0, stream>>>(A, rowstart, elist, dinv, b2, B, N);
    // heads + routing + log_softmax
    heads_kernel<<<head_grid, 256, 0, stream>>>(B, Wdet, bdet, Wund, bund,
                                                Wroot, broot, out, N);
}

// Round 3
// 299.795 us; speedup vs baseline: 1.2912x; 1.2912x over previous
//
#include <hip/hip_runtime.h>
#include <math.h>

#define HDIM 128
#define SCHUNK 256

// ---------------------------------------------------------------- utilities
__device__ __forceinline__ int load_idx(const void* ei, long long E, int which,
                                        long long e, int is64) {
    if (is64) {
        const long long* p = (const long long*)ei;
        return (int)p[(long long)which * E + e];
    } else {
        const int* p = (const int*)ei;
        return p[(long long)which * E + e];
    }
}

// Clamp any value to a guaranteed-finite float (nan -> -3e38).
__device__ __forceinline__ float fin(float x) {
    if (!(x > -3.0e38f)) return -3.0e38f;  // catches nan and -inf
    if (x > 3.0e38f) return 3.0e38f;
    return x;
}

// Detect int64 vs int32 edge_index: sample high dwords of first 4096 slots.
__global__ void detect64_kernel(const unsigned* u, long long n_dwords,
                                int* flag) {
    __shared__ int any;
    if (threadIdx.x == 0) any = 0;
    __syncthreads();
    long long slots = n_dwords / 2;
    long long cap = slots < 4096 ? slots : 4096;
    for (long long i = threadIdx.x; i < cap; i += blockDim.x)
        if (u[2 * i + 1] != 0u) any = 1;  // benign race, monotonic
    __syncthreads();
    if (threadIdx.x == 0) *flag = any ? 0 : 1;
}

__global__ void zero_cnt_kernel(int* cnt, int n) {
    int i = blockIdx.x * blockDim.x + threadIdx.x;
    int stride = gridDim.x * blockDim.x;
    for (; i < n; i += stride) cnt[i] = 0;
}

__global__ void count_edges_kernel(const void* ei, const int* flag64, int* cnt,
                                   long long E, int n) {
    long long e = (long long)blockIdx.x * blockDim.x + threadIdx.x;
    long long stride = (long long)gridDim.x * blockDim.x;
    int is64 = *flag64;
    for (; e < E; e += stride) {
        int d = load_idx(ei, E, 1, e, is64);
        if ((unsigned)d < (unsigned)n) atomicAdd(&cnt[d], 1);
    }
}

// ------------------------------------------------ 3-phase multi-block scan
// p1: per-block (SCHUNK-elem chunk) sums
__global__ __launch_bounds__(SCHUNK) void scan_p1_kernel(
        const int* __restrict__ cnt, int* __restrict__ bsum, int n) {
    __shared__ int sd[SCHUNK];
    int b = blockIdx.x, t = threadIdx.x;
    int i = b * SCHUNK + t;
    sd[t] = (i < n) ? cnt[i] : 0;
    __syncthreads();
    for (int off = SCHUNK / 2; off > 0; off >>= 1) {
        if (t < off) sd[t] += sd[t + off];
        __syncthreads();
    }
    if (t == 0) bsum[b] = sd[0];
}

// p2: exclusive scan of the nb block sums (nb ~ 196, single tiny block)
__global__ __launch_bounds__(SCHUNK) void scan_p2_kernel(
        const int* __restrict__ bsum, int* __restrict__ boff, int nb,
        int* __restrict__ rowstart_n) {
    __shared__ int sd[SCHUNK];
    __shared__ int s_carry;
    int t = threadIdx.x;
    if (t == 0) s_carry = 0;
    __syncthreads();
    int nloop = (nb + SCHUNK - 1) / SCHUNK;
    for (int bi = 0; bi < nloop; ++bi) {
        int i = bi * SCHUNK + t;
        int v = (i < nb) ? bsum[i] : 0;
        sd[t] = v;
        __syncthreads();
        for (int off = 1; off < SCHUNK; off <<= 1) {
            int add = (t >= off) ? sd[t - off] : 0;
            __syncthreads();
            sd[t] += add;
            __syncthreads();
        }
        int carry = s_carry;
        if (i < nb) boff[i] = carry + sd[t] - v;
        __syncthreads();
        if (t == SCHUNK - 1) s_carry = carry + sd[SCHUNK - 1];
        __syncthreads();
    }
    if (t == 0) *rowstart_n = s_carry;  // rowstart[n] = total
}

// p3: local exclusive scan + block base; also dinv = rsqrt(deg+1)
__global__ __launch_bounds__(SCHUNK) void scan_p3_kernel(
        const int* __restrict__ cnt, const int* __restrict__ boff,
        int* __restrict__ rowstart, int* __restrict__ wcur,
        float* __restrict__ dinv, int n) {
    __shared__ int sd[SCHUNK];
    int b = blockIdx.x, t = threadIdx.x;
    int i = b * SCHUNK + t;
    int v = (i < n) ? cnt[i] : 0;
    sd[t] = v;
    __syncthreads();
    for (int off = 1; off < SCHUNK; off <<= 1) {
        int add = (t >= off) ? sd[t - off] : 0;
        __syncthreads();
        sd[t] += add;
        __syncthreads();
    }
    if (i < n) {
        int excl = boff[b] + sd[t] - v;
        rowstart[i] = excl;
        wcur[i] = excl;
        dinv[i] = rsqrtf((float)(v + 1));
    }
}

__global__ void fill_elist_kernel(const void* ei, const int* flag64, int* wcur,
                                  int* elist, long long E, int n) {
    long long e = (long long)blockIdx.x * blockDim.x + threadIdx.x;
    long long stride = (long long)gridDim.x * blockDim.x;
    int is64 = *flag64;
    for (; e < E; e += stride) {
        int s = load_idx(ei, E, 0, e, is64);
        int d = load_idx(ei, E, 1, e, is64);
        if ((unsigned)d >= (unsigned)n) continue;      // matches count guard
        if ((unsigned)s >= (unsigned)n) s = d;         // safe fallback
        int pos = atomicAdd(&wcur[d], 1);
        if (pos >= 0 && pos < (int)E) elist[pos] = s;  // never scribble OOB
    }
}

// ------------------------------------------------------------------- GEMM
// Y[r][c] = dinv[r] * sum_k X[r][k] * W[k][c]     (N x 128) @ (128 x 128)
#define GFMA(cc, xs)                                                           \
    cc.x = fmaf(xs, wv.x, cc.x);                                               \
    cc.y = fmaf(xs, wv.y, cc.y);                                               \
    cc.z = fmaf(xs, wv.z, cc.z);                                               \
    cc.w = fmaf(xs, wv.w, cc.w);

#define GSTORE(cc, j)                                                          \
    {                                                                          \
        int gr = R0 + row0 + (j);                                              \
        if (gr < n) {                                                          \
            float dv = dinv[gr];                                               \
            float4 o;                                                          \
            o.x = dv * cc.x; o.y = dv * cc.y; o.z = dv * cc.z; o.w = dv * cc.w;\
            *(float4*)(Y + (size_t)gr * HDIM + col0) = o;                      \
        }                                                                      \
    }

__global__ __launch_bounds__(256) void gemm_scaled_kernel(
        const float* __restrict__ X, const float* __restrict__ Wg,
        const float* __restrict__ dinv, float* __restrict__ Y, int n) {
    __shared__ float xT[HDIM][32];
    int R0 = blockIdx.x * 32;
    int t = threadIdx.x;
    {   // stage x tile transposed: xT[k][r] = X[R0+r][k]
        int r = t & 31, kq8 = t >> 5;
        const float* xr = X + (size_t)(R0 + r) * HDIM;
        bool ok = (R0 + r) < n;
#pragma unroll
        for (int p = 0; p < 4; ++p) {
            int kq = kq8 + p * 8;
            float4 xv = ok ? ((const float4*)xr)[kq] : make_float4(0.f, 0.f, 0.f, 0.f);
            xT[kq * 4 + 0][r] = xv.x;
            xT[kq * 4 + 1][r] = xv.y;
            xT[kq * 4 + 2][r] = xv.z;
            xT[kq * 4 + 3][r] = xv.w;
        }
    }
    __syncthreads();
    int w = t >> 6, lane = t & 63;
    int rg = w >> 1, cg = w & 1;
    int rq = lane >> 4, cq = lane & 15;
    int row0 = rg * 16 + rq * 4;
    int col0 = cg * 64 + cq * 4;
    const float* Wp = Wg + col0;
    float4 c0 = make_float4(0.f, 0.f, 0.f, 0.f), c1 = c0, c2 = c0, c3 = c0;
#pragma unroll 4
    for (int k = 0; k < HDIM; ++k) {
        float4 wv = *(const float4*)(Wp + (size_t)k * HDIM);
        float4 xv = *(const float4*)(&xT[k][row0]);
        GFMA(c0, xv.x);
        GFMA(c1, xv.y);
        GFMA(c2, xv.z);
        GFMA(c3, xv.w);
    }
    GSTORE(c0, 0);
    GSTORE(c1, 1);
    GSTORE(c2, 2);
    GSTORE(c3, 3);
}

// -------------------------------------------------------------------- pull
// H[v] = relu(bias + dinv[v] * (Y[v] + sum_{incoming e} Y[src_e]))
__global__ __launch_bounds__(256) void pull_relu_kernel(
        const float* __restrict__ Y, const int* __restrict__ rowstart,
        const int* __restrict__ elist, const float* __restrict__ dinv,
        const float* __restrict__ bias, float* __restrict__ H, int n) {
    int gw = (int)((blockIdx.x * blockDim.x + threadIdx.x) >> 6);
    int lane = threadIdx.x & 63;
    if (gw >= n) return;
    int v = gw;
    float2 a0 = ((const float2*)(Y + (size_t)v * HDIM))[lane];  // self loop
    float2 a1 = make_float2(0.f, 0.f), a2 = a1, a3 = a1;
    int i = rowstart[v], e = rowstart[v + 1];
    for (; i + 4 <= e; i += 4) {
        int sA = elist[i], sB = elist[i + 1], sC = elist[i + 2], sD = elist[i + 3];
        if ((unsigned)sA >= (unsigned)n) sA = v;
        if ((unsigned)sB >= (unsigned)n) sB = v;
        if ((unsigned)sC >= (unsigned)n) sC = v;
        if ((unsigned)sD >= (unsigned)n) sD = v;
        float2 mA = ((const float2*)(Y + (size_t)sA * HDIM))[lane];
        float2 mB = ((const float2*)(Y + (size_t)sB * HDIM))[lane];
        float2 mC = ((const float2*)(Y + (size_t)sC * HDIM))[lane];
        float2 mD = ((const float2*)(Y + (size_t)sD * HDIM))[lane];
        a0.x += mA.x; a0.y += mA.y;
        a1.x += mB.x; a1.y += mB.y;
        a2.x += mC.x; a2.y += mC.y;
        a3.x += mD.x; a3.y += mD.y;
    }
    for (; i < e; ++i) {
        int s = elist[i];
        if ((unsigned)s >= (unsigned)n) s = v;
        float2 m = ((const float2*)(Y + (size_t)s * HDIM))[lane];
        a0.x += m.x; a0.y += m.y;
    }
    float dv = dinv[v];
    float2 b = ((const float2*)bias)[lane];
    float hx = fmaxf(fmaf(dv, a0.x + a1.x + a2.x + a3.x, b.x), 0.f);
    float hy = fmaxf(fmaf(dv, a0.y + a1.y + a2.y + a3.y, b.y), 0.f);
    ((float2*)(H + (size_t)v * HDIM))[lane] = make_float2(hx, hy);
}

// ------------------------------------------------------------------- heads
#define SENT (-3.0e38f)

#define HEAD_STEP(hk, k)                                                       \
    {                                                                          \
        float2 wd = ((const float2*)Wdet)[k];                                  \
        d0 = fmaf(hk, wd.x, d0); d1 = fmaf(hk, wd.y, d1);                      \
        float2 wu = ((const float2*)Wund)[k];                                  \
        u0 = fmaf(hk, wu.x, u0); u1 = fmaf(hk, wu.y, u1);                      \
        float4 wr = ((const float4*)Wroot)[k];                                 \
        r0 = fmaf(hk, wr.x, r0); r1 = fmaf(hk, wr.y, r1);                      \
        r2 = fmaf(hk, wr.z, r2); r3 = fmaf(hk, wr.w, r3);                      \
    }

__global__ __launch_bounds__(256) void heads_kernel(
        const float* __restrict__ Hh, const float* __restrict__ Wdet,
        const float* __restrict__ bdet, const float* __restrict__ Wund,
        const float* __restrict__ bund, const float* __restrict__ Wroot,
        const float* __restrict__ broot, float* __restrict__ out, int n) {
    int nid = blockIdx.x * blockDim.x + threadIdx.x;
    if (nid >= n) return;
    const float4* hp = (const float4*)(Hh + (size_t)nid * HDIM);
    float d0 = 0.f, d1 = 0.f, u0 = 0.f, u1 = 0.f;
    float r0 = 0.f, r1 = 0.f, r2 = 0.f, r3 = 0.f;
#pragma unroll 8
    for (int kq = 0; kq < 32; ++kq) {
        float4 hv = hp[kq];
        HEAD_STEP(hv.x, kq * 4 + 0);
        HEAD_STEP(hv.y, kq * 4 + 1);
        HEAD_STEP(hv.z, kq * 4 + 2);
        HEAD_STEP(hv.w, kq * 4 + 3);
    }
    d0 += bdet[0]; d1 += bdet[1];
    u0 += bund[0]; u1 += bund[1];
    r0 += broot[0]; r1 += broot[1]; r2 += broot[2]; r3 += broot[3];

    // det log_softmax
    float m = fmaxf(d0, d1);
    float lse = m + logf(expf(d0 - m) + expf(d1 - m));
    out[(size_t)nid * 2 + 0] = fin(d0 - lse);
    out[(size_t)nid * 2 + 1] = fin(d1 - lse);

    float* ro = out + 2 * (size_t)n + (size_t)nid * 5;
    if (d1 > d0) {  // argmax == 1 (strict: tie -> index 0 -> false)
        float mm = fmaxf(fmaxf(r0, r1), fmaxf(r2, r3));
        float l2 = mm + logf(expf(r0 - mm) + expf(r1 - mm) + expf(r2 - mm) +
                             expf(r3 - mm));
        ro[0] = SENT;  // reference: -inf (finite sentinel avoids inf-inf=nan)
        ro[1] = fin(r0 - l2);
        ro[2] = fin(r1 - l2);
        ro[3] = fin(r2 - l2);
        ro[4] = fin(r3 - l2);
    } else {
        float mm = fmaxf(u0, u1);
        float l2 = mm + logf(expf(u0 - mm) + expf(u1 - mm));
        ro[0] = fin(u0 - l2);
        ro[1] = fin(u1 - l2);
        ro[2] = SENT;
        ro[3] = SENT;
        ro[4] = SENT;
    }
}

__global__ void ws_too_small_kernel(float* out, int n) {
    int i = blockIdx.x * blockDim.x + threadIdx.x;
    if (i < n) out[i] = -12345.0f;  // sentinel: workspace was insufficient
}

// ----------------------------------------------------------------- launch
extern "C" void kernel_launch(void* const* d_in, const int* in_sizes, int n_in,
                              void* d_out, int out_size, void* d_ws,
                              size_t ws_size, hipStream_t stream) {
    const float* x     = (const float*)d_in[0];
    const void*  ei    = d_in[1];
    const float* W1    = (const float*)d_in[2];
    const float* b1    = (const float*)d_in[3];
    const float* W2    = (const float*)d_in[4];
    const float* b2    = (const float*)d_in[5];
    const float* Wdet  = (const float*)d_in[6];
    const float* bdet  = (const float*)d_in[7];
    const float* Wund  = (const float*)d_in[8];
    const float* bund  = (const float*)d_in[9];
    const float* Wroot = (const float*)d_in[10];
    const float* broot = (const float*)d_in[11];
    int N = in_sizes[0] / HDIM;       // 50000
    long long E = in_sizes[1] / 2;    // 800000
    float* out = (float*)d_out;
    int nb = (N + SCHUNK - 1) / SCHUNK;  // scan blocks (196)

    // workspace carve (256B aligned)
    size_t off = 0;
    auto carve = [&](size_t bytes) -> void* {
        void* p = (char*)d_ws + off;
        off += (bytes + 255) & ~(size_t)255;
        return p;
    };
    float* A        = (float*)carve((size_t)N * HDIM * 4);
    float* B        = (float*)carve((size_t)N * HDIM * 4);
    float* dinv     = (float*)carve((size_t)N * 4);
    int*   cnt      = (int*)carve((size_t)N * 4);
    int*   rowstart = (int*)carve((size_t)(N + 1) * 4);
    int*   wcur     = (int*)carve((size_t)N * 4);
    int*   elist    = (int*)carve((size_t)E * 4);
    int*   bsum     = (int*)carve((size_t)nb * 4);
    int*   boff     = (int*)carve((size_t)nb * 4);
    int*   flag64   = (int*)carve(256);

    if (off > ws_size) {
        ws_too_small_kernel<<<(out_size + 255) / 256, 256, 0, stream>>>(out, out_size);
        return;
    }

    // CSR build
    detect64_kernel<<<1, 256, 0, stream>>>((const unsigned*)ei,
                                           (long long)in_sizes[1], flag64);
    zero_cnt_kernel<<<256, 256, 0, stream>>>(cnt, N);
    count_edges_kernel<<<2048, 256, 0, stream>>>(ei, flag64, cnt, E, N);
    scan_p1_kernel<<<nb, SCHUNK, 0, stream>>>(cnt, bsum, N);
    scan_p2_kernel<<<1, SCHUNK, 0, stream>>>(bsum, boff, nb, rowstart + N);
    scan_p3_kernel<<<nb, SCHUNK, 0, stream>>>(cnt, boff, rowstart, wcur, dinv, N);
    fill_elist_kernel<<<2048, 256, 0, stream>>>(ei, flag64, wcur, elist, E, N);

    int gemm_grid = (N + 31) / 32;
    int pull_grid = (N + 3) / 4;      // 4 waves (nodes) per 256-thread block
    int head_grid = (N + 255) / 256;

    // layer 1: A = dinv * (x @ W1);  B = relu(b1 + dinv*(A_self + gather))
    gemm_scaled_kernel<<<gemm_grid, 256, 0, stream>>>(x, W1, dinv, A, N);
    pull_relu_kernel<<<pull_grid, 256, 0, stream>>>(A, rowstart, elist, dinv, b1, B, N);
    // layer 2: A = dinv * (B @ W2);  B = relu(b2 + dinv*(A_self + gather))
    gemm_scaled_kernel<<<gemm_grid, 256, 0, stream>>>(B, W2, dinv, A, N);
    pull_relu_kernel<<<pull_grid, 256, 0, stream>>>(A, rowstart, elist, dinv, b2, B, N);
    // heads + routing + log_softmax
    heads_kernel<<<head_grid, 256, 0, stream>>>(B, Wdet, bdet, Wund, bund,
                                                Wroot, broot, out, N);
}

// Round 4
// 267.784 us; speedup vs baseline: 1.4456x; 1.1195x over previous
//
#include <hip/hip_runtime.h>
#include <hip/hip_fp16.h>
#include <math.h>

#define HDIM 128
#define SCHUNK 256

// ---------------------------------------------------------------- utilities
__device__ __forceinline__ int load_idx(const void* ei, long long E, int which,
                                        long long e, int is64) {
    if (is64) {
        const long long* p = (const long long*)ei;
        return (int)p[(long long)which * E + e];
    } else {
        const int* p = (const int*)ei;
        return p[(long long)which * E + e];
    }
}

// Clamp any value to a guaranteed-finite float (nan -> -3e38).
__device__ __forceinline__ float fin(float x) {
    if (!(x > -3.0e38f)) return -3.0e38f;  // catches nan and -inf
    if (x > 3.0e38f) return 3.0e38f;
    return x;
}

// Detect int64 vs int32 edge_index: sample high dwords of first 4096 slots.
__global__ void detect64_kernel(const unsigned* u, long long n_dwords,
                                int* flag) {
    __shared__ int any;
    if (threadIdx.x == 0) any = 0;
    __syncthreads();
    long long slots = n_dwords / 2;
    long long cap = slots < 4096 ? slots : 4096;
    for (long long i = threadIdx.x; i < cap; i += blockDim.x)
        if (u[2 * i + 1] != 0u) any = 1;  // benign race, monotonic
    __syncthreads();
    if (threadIdx.x == 0) *flag = any ? 0 : 1;
}

__global__ void zero_cnt_kernel(int* cnt, int n) {
    int i = blockIdx.x * blockDim.x + threadIdx.x;
    int stride = gridDim.x * blockDim.x;
    for (; i < n; i += stride) cnt[i] = 0;
}

__global__ void count_edges_kernel(const void* ei, const int* flag64, int* cnt,
                                   long long E, int n) {
    long long e = (long long)blockIdx.x * blockDim.x + threadIdx.x;
    long long stride = (long long)gridDim.x * blockDim.x;
    int is64 = *flag64;
    for (; e < E; e += stride) {
        int d = load_idx(ei, E, 1, e, is64);
        if ((unsigned)d < (unsigned)n) atomicAdd(&cnt[d], 1);
    }
}

// ------------------------------------------------ 3-phase multi-block scan
__global__ __launch_bounds__(SCHUNK) void scan_p1_kernel(
        const int* __restrict__ cnt, int* __restrict__ bsum, int n) {
    __shared__ int sd[SCHUNK];
    int b = blockIdx.x, t = threadIdx.x;
    int i = b * SCHUNK + t;
    sd[t] = (i < n) ? cnt[i] : 0;
    __syncthreads();
    for (int off = SCHUNK / 2; off > 0; off >>= 1) {
        if (t < off) sd[t] += sd[t + off];
        __syncthreads();
    }
    if (t == 0) bsum[b] = sd[0];
}

__global__ __launch_bounds__(SCHUNK) void scan_p2_kernel(
        const int* __restrict__ bsum, int* __restrict__ boff, int nb,
        int* __restrict__ rowstart_n) {
    __shared__ int sd[SCHUNK];
    __shared__ int s_carry;
    int t = threadIdx.x;
    if (t == 0) s_carry = 0;
    __syncthreads();
    int nloop = (nb + SCHUNK - 1) / SCHUNK;
    for (int bi = 0; bi < nloop; ++bi) {
        int i = bi * SCHUNK + t;
        int v = (i < nb) ? bsum[i] : 0;
        sd[t] = v;
        __syncthreads();
        for (int off = 1; off < SCHUNK; off <<= 1) {
            int add = (t >= off) ? sd[t - off] : 0;
            __syncthreads();
            sd[t] += add;
            __syncthreads();
        }
        int carry = s_carry;
        if (i < nb) boff[i] = carry + sd[t] - v;
        __syncthreads();
        if (t == SCHUNK - 1) s_carry = carry + sd[SCHUNK - 1];
        __syncthreads();
    }
    if (t == 0) *rowstart_n = s_carry;  // rowstart[n] = total
}

__global__ __launch_bounds__(SCHUNK) void scan_p3_kernel(
        const int* __restrict__ cnt, const int* __restrict__ boff,
        int* __restrict__ rowstart, int* __restrict__ wcur,
        float* __restrict__ dinv, int n) {
    __shared__ int sd[SCHUNK];
    int b = blockIdx.x, t = threadIdx.x;
    int i = b * SCHUNK + t;
    int v = (i < n) ? cnt[i] : 0;
    sd[t] = v;
    __syncthreads();
    for (int off = 1; off < SCHUNK; off <<= 1) {
        int add = (t >= off) ? sd[t - off] : 0;
        __syncthreads();
        sd[t] += add;
        __syncthreads();
    }
    if (i < n) {
        int excl = boff[b] + sd[t] - v;
        rowstart[i] = excl;
        wcur[i] = excl;
        dinv[i] = rsqrtf((float)(v + 1));
    }
}

__global__ void fill_elist_kernel(const void* ei, const int* flag64, int* wcur,
                                  int* elist, long long E, int n) {
    long long e = (long long)blockIdx.x * blockDim.x + threadIdx.x;
    long long stride = (long long)gridDim.x * blockDim.x;
    int is64 = *flag64;
    for (; e < E; e += stride) {
        int s = load_idx(ei, E, 0, e, is64);
        int d = load_idx(ei, E, 1, e, is64);
        if ((unsigned)d >= (unsigned)n) continue;      // matches count guard
        if ((unsigned)s >= (unsigned)n) s = d;         // safe fallback
        int pos = atomicAdd(&wcur[d], 1);
        if (pos >= 0 && pos < (int)E) elist[pos] = s;  // never scribble OOB
    }
}

// ------------------------------------------------------------------- GEMM
// Y[r][c] = dinv[r] * sum_k X[r][k] * W[k][c]; also writes fp16 copy Yh.
#define GFMA(cc, xs)                                                           \
    cc.x = fmaf(xs, wv.x, cc.x);                                               \
    cc.y = fmaf(xs, wv.y, cc.y);                                               \
    cc.z = fmaf(xs, wv.z, cc.z);                                               \
    cc.w = fmaf(xs, wv.w, cc.w);

#define GSTORE(cc, j)                                                          \
    {                                                                          \
        int gr = R0 + row0 + (j);                                              \
        if (gr < n) {                                                          \
            float dv = dinv[gr];                                               \
            float4 o;                                                          \
            o.x = dv * cc.x; o.y = dv * cc.y; o.z = dv * cc.z; o.w = dv * cc.w;\
            *(float4*)(Y + (size_t)gr * HDIM + col0) = o;                      \
            union { __half2 h2[2]; float2 f2; } pk;                            \
            pk.h2[0] = __floats2half2_rn(o.x, o.y);                            \
            pk.h2[1] = __floats2half2_rn(o.z, o.w);                            \
            *(float2*)(Yh + (size_t)gr * HDIM + col0) = pk.f2;                 \
        }                                                                      \
    }

__global__ __launch_bounds__(256) void gemm_scaled_kernel(
        const float* __restrict__ X, const float* __restrict__ Wg,
        const float* __restrict__ dinv, float* __restrict__ Y,
        __half* __restrict__ Yh, int n) {
    __shared__ float xT[HDIM][32];
    int R0 = blockIdx.x * 32;
    int t = threadIdx.x;
    {   // stage x tile transposed: xT[k][r] = X[R0+r][k]
        int r = t & 31, kq8 = t >> 5;
        const float* xr = X + (size_t)(R0 + r) * HDIM;
        bool ok = (R0 + r) < n;
#pragma unroll
        for (int p = 0; p < 4; ++p) {
            int kq = kq8 + p * 8;
            float4 xv = ok ? ((const float4*)xr)[kq] : make_float4(0.f, 0.f, 0.f, 0.f);
            xT[kq * 4 + 0][r] = xv.x;
            xT[kq * 4 + 1][r] = xv.y;
            xT[kq * 4 + 2][r] = xv.z;
            xT[kq * 4 + 3][r] = xv.w;
        }
    }
    __syncthreads();
    int w = t >> 6, lane = t & 63;
    int rg = w >> 1, cg = w & 1;
    int rq = lane >> 4, cq = lane & 15;
    int row0 = rg * 16 + rq * 4;
    int col0 = cg * 64 + cq * 4;
    const float* Wp = Wg + col0;
    float4 c0 = make_float4(0.f, 0.f, 0.f, 0.f), c1 = c0, c2 = c0, c3 = c0;
#pragma unroll 4
    for (int k = 0; k < HDIM; ++k) {
        float4 wv = *(const float4*)(Wp + (size_t)k * HDIM);
        float4 xv = *(const float4*)(&xT[k][row0]);
        GFMA(c0, xv.x);
        GFMA(c1, xv.y);
        GFMA(c2, xv.z);
        GFMA(c3, xv.w);
    }
    GSTORE(c0, 0);
    GSTORE(c1, 1);
    GSTORE(c2, 2);
    GSTORE(c3, 3);
}

// ---------------------------------------------------------- shared gather
// Aggregates (self f32 + fp16 neighbor msgs) for node v; returns float2/lane.
__device__ __forceinline__ float2 gather_node(
        const float* __restrict__ Y, const __half* __restrict__ Yh,
        const int* __restrict__ rowstart, const int* __restrict__ elist,
        int v, int lane, int n) {
    float2 a0 = ((const float2*)(Y + (size_t)v * HDIM))[lane];  // self (f32)
    float2 a1 = make_float2(0.f, 0.f), a2 = a1, a3 = a1;
    int i = rowstart[v], e = rowstart[v + 1];
    for (; i + 4 <= e; i += 4) {
        int sA = elist[i], sB = elist[i + 1], sC = elist[i + 2], sD = elist[i + 3];
        if ((unsigned)sA >= (unsigned)n) sA = v;
        if ((unsigned)sB >= (unsigned)n) sB = v;
        if ((unsigned)sC >= (unsigned)n) sC = v;
        if ((unsigned)sD >= (unsigned)n) sD = v;
        float2 mA = __half22float2(((const __half2*)(Yh + (size_t)sA * HDIM))[lane]);
        float2 mB = __half22float2(((const __half2*)(Yh + (size_t)sB * HDIM))[lane]);
        float2 mC = __half22float2(((const __half2*)(Yh + (size_t)sC * HDIM))[lane]);
        float2 mD = __half22float2(((const __half2*)(Yh + (size_t)sD * HDIM))[lane]);
        a0.x += mA.x; a0.y += mA.y;
        a1.x += mB.x; a1.y += mB.y;
        a2.x += mC.x; a2.y += mC.y;
        a3.x += mD.x; a3.y += mD.y;
    }
    for (; i < e; ++i) {
        int s = elist[i];
        if ((unsigned)s >= (unsigned)n) s = v;
        float2 m = __half22float2(((const __half2*)(Yh + (size_t)s * HDIM))[lane]);
        a0.x += m.x; a0.y += m.y;
    }
    return make_float2(a0.x + a1.x + a2.x + a3.x, a0.y + a1.y + a2.y + a3.y);
}

// -------------------------------------------------------------------- pull
// H[v] = relu(bias + dinv[v] * (Y[v] + sum msgs))      (layer 1)
__global__ __launch_bounds__(256) void pull_relu_kernel(
        const float* __restrict__ Y, const __half* __restrict__ Yh,
        const int* __restrict__ rowstart, const int* __restrict__ elist,
        const float* __restrict__ dinv, const float* __restrict__ bias,
        float* __restrict__ H, int n) {
    int v = (int)((blockIdx.x * blockDim.x + threadIdx.x) >> 6);
    int lane = threadIdx.x & 63;
    if (v >= n) return;
    float2 a = gather_node(Y, Yh, rowstart, elist, v, lane, n);
    float dv = dinv[v];
    float2 b = ((const float2*)bias)[lane];
    float hx = fmaxf(fmaf(dv, a.x, b.x), 0.f);
    float hy = fmaxf(fmaf(dv, a.y, b.y), 0.f);
    ((float2*)(H + (size_t)v * HDIM))[lane] = make_float2(hx, hy);
}

// ------------------------------------------- fused pull (layer 2) + heads
#define SENT (-3.0e38f)
#define BFLY(p) \
    p += __shfl_xor(p, 32); p += __shfl_xor(p, 16); p += __shfl_xor(p, 8); \
    p += __shfl_xor(p, 4);  p += __shfl_xor(p, 2);  p += __shfl_xor(p, 1);

__global__ __launch_bounds__(256) void pull_heads_kernel(
        const float* __restrict__ Y, const __half* __restrict__ Yh,
        const int* __restrict__ rowstart, const int* __restrict__ elist,
        const float* __restrict__ dinv, const float* __restrict__ bias,
        const float* __restrict__ Wdet, const float* __restrict__ bdet,
        const float* __restrict__ Wund, const float* __restrict__ bund,
        const float* __restrict__ Wroot, const float* __restrict__ broot,
        float* __restrict__ out, int n) {
    int v = (int)((blockIdx.x * blockDim.x + threadIdx.x) >> 6);
    int lane = threadIdx.x & 63;
    if (v >= n) return;
    float2 a = gather_node(Y, Yh, rowstart, elist, v, lane, n);
    float dv = dinv[v];
    float2 b = ((const float2*)bias)[lane];
    float hx = fmaxf(fmaf(dv, a.x, b.x), 0.f);   // h[2*lane]
    float hy = fmaxf(fmaf(dv, a.y, b.y), 0.f);   // h[2*lane+1]

    // per-lane head partials: rows 2l,2l+1 of each weight matrix
    float4 wd  = ((const float4*)Wdet)[lane];         // [2l][0],[2l][1],[2l+1][0],[2l+1][1]
    float4 wu  = ((const float4*)Wund)[lane];
    float4 wr0 = ((const float4*)Wroot)[2 * lane];     // row 2l
    float4 wr1 = ((const float4*)Wroot)[2 * lane + 1]; // row 2l+1
    float pd0 = hx * wd.x + hy * wd.z;
    float pd1 = hx * wd.y + hy * wd.w;
    float pu0 = hx * wu.x + hy * wu.z;
    float pu1 = hx * wu.y + hy * wu.w;
    float pr0 = hx * wr0.x + hy * wr1.x;
    float pr1 = hx * wr0.y + hy * wr1.y;
    float pr2 = hx * wr0.z + hy * wr1.z;
    float pr3 = hx * wr0.w + hy * wr1.w;
    BFLY(pd0); BFLY(pd1); BFLY(pu0); BFLY(pu1);
    BFLY(pr0); BFLY(pr1); BFLY(pr2); BFLY(pr3);

    if (lane == 0) {
        float d0 = pd0 + bdet[0], d1 = pd1 + bdet[1];
        float u0 = pu0 + bund[0], u1 = pu1 + bund[1];
        float r0 = pr0 + broot[0], r1 = pr1 + broot[1];
        float r2 = pr2 + broot[2], r3 = pr3 + broot[3];
        float m = fmaxf(d0, d1);
        float lse = m + logf(expf(d0 - m) + expf(d1 - m));
        out[(size_t)v * 2 + 0] = fin(d0 - lse);
        out[(size_t)v * 2 + 1] = fin(d1 - lse);
        float* ro = out + 2 * (size_t)n + (size_t)v * 5;
        if (d1 > d0) {  // argmax == 1 (tie -> index 0 -> false)
            float mm = fmaxf(fmaxf(r0, r1), fmaxf(r2, r3));
            float l2 = mm + logf(expf(r0 - mm) + expf(r1 - mm) +
                                 expf(r2 - mm) + expf(r3 - mm));
            ro[0] = SENT;  // reference: -inf (finite sentinel, inf-inf=nan)
            ro[1] = fin(r0 - l2);
            ro[2] = fin(r1 - l2);
            ro[3] = fin(r2 - l2);
            ro[4] = fin(r3 - l2);
        } else {
            float mm = fmaxf(u0, u1);
            float l2 = mm + logf(expf(u0 - mm) + expf(u1 - mm));
            ro[0] = fin(u0 - l2);
            ro[1] = fin(u1 - l2);
            ro[2] = SENT;
            ro[3] = SENT;
            ro[4] = SENT;
        }
    }
}

__global__ void ws_too_small_kernel(float* out, int n) {
    int i = blockIdx.x * blockDim.x + threadIdx.x;
    if (i < n) out[i] = -12345.0f;  // sentinel: workspace was insufficient
}

// ----------------------------------------------------------------- launch
extern "C" void kernel_launch(void* const* d_in, const int* in_sizes, int n_in,
                              void* d_out, int out_size, void* d_ws,
                              size_t ws_size, hipStream_t stream) {
    const float* x     = (const float*)d_in[0];
    const void*  ei    = d_in[1];
    const float* W1    = (const float*)d_in[2];
    const float* b1    = (const float*)d_in[3];
    const float* W2    = (const float*)d_in[4];
    const float* b2    = (const float*)d_in[5];
    const float* Wdet  = (const float*)d_in[6];
    const float* bdet  = (const float*)d_in[7];
    const float* Wund  = (const float*)d_in[8];
    const float* bund  = (const float*)d_in[9];
    const float* Wroot = (const float*)d_in[10];
    const float* broot = (const float*)d_in[11];
    int N = in_sizes[0] / HDIM;       // 50000
    long long E = in_sizes[1] / 2;    // 800000
    float* out = (float*)d_out;
    int nb = (N + SCHUNK - 1) / SCHUNK;

    // workspace carve (256B aligned)
    size_t off = 0;
    auto carve = [&](size_t bytes) -> void* {
        void* p = (char*)d_ws + off;
        off += (bytes + 255) & ~(size_t)255;
        return p;
    };
    float*  A        = (float*)carve((size_t)N * HDIM * 4);
    float*  B        = (float*)carve((size_t)N * HDIM * 4);
    __half* Ah       = (__half*)carve((size_t)N * HDIM * 2);
    float*  dinv     = (float*)carve((size_t)N * 4);
    int*    cnt      = (int*)carve((size_t)N * 4);
    int*    rowstart = (int*)carve((size_t)(N + 1) * 4);
    int*    wcur     = (int*)carve((size_t)N * 4);
    int*    elist    = (int*)carve((size_t)E * 4);
    int*    bsum     = (int*)carve((size_t)nb * 4);
    int*    boff     = (int*)carve((size_t)nb * 4);
    int*    flag64   = (int*)carve(256);

    if (off > ws_size) {
        ws_too_small_kernel<<<(out_size + 255) / 256, 256, 0, stream>>>(out, out_size);
        return;
    }

    // CSR build
    detect64_kernel<<<1, 256, 0, stream>>>((const unsigned*)ei,
                                           (long long)in_sizes[1], flag64);
    zero_cnt_kernel<<<256, 256, 0, stream>>>(cnt, N);
    count_edges_kernel<<<2048, 256, 0, stream>>>(ei, flag64, cnt, E, N);
    scan_p1_kernel<<<nb, SCHUNK, 0, stream>>>(cnt, bsum, N);
    scan_p2_kernel<<<1, SCHUNK, 0, stream>>>(bsum, boff, nb, rowstart + N);
    scan_p3_kernel<<<nb, SCHUNK, 0, stream>>>(cnt, boff, rowstart, wcur, dinv, N);
    fill_elist_kernel<<<2048, 256, 0, stream>>>(ei, flag64, wcur, elist, E, N);

    int gemm_grid = (N + 31) / 32;
    int pull_grid = (N + 3) / 4;      // 4 waves (nodes) per 256-thread block

    // layer 1: A,Ah = dinv * (x @ W1);  B = relu(b1 + dinv*(self + gather))
    gemm_scaled_kernel<<<gemm_grid, 256, 0, stream>>>(x, W1, dinv, A, Ah, N);
    pull_relu_kernel<<<pull_grid, 256, 0, stream>>>(A, Ah, rowstart, elist,
                                                    dinv, b1, B, N);
    // layer 2: A,Ah = dinv * (B @ W2); fused pull + heads -> out
    gemm_scaled_kernel<<<gemm_grid, 256, 0, stream>>>(B, W2, dinv, A, Ah, N);
    pull_heads_kernel<<<pull_grid, 256, 0, stream>>>(A, Ah, rowstart, elist,
                                                     dinv, b2, Wdet, bdet,
                                                     Wund, bund, Wroot, broot,
                                                     out, N);
}

// Round 5
// 259.738 us; speedup vs baseline: 1.4903x; 1.0310x over previous
//
#include <hip/hip_runtime.h>
#include <hip/hip_fp16.h>
#include <math.h>

#define HDIM 128
#define SCHUNK 256
#define EB 8  // edges per thread in count/fill

// ---------------------------------------------------------------- utilities
__device__ __forceinline__ int load_idx(const void* ei, long long E, int which,
                                        long long e, int is64) {
    if (is64) {
        const long long* p = (const long long*)ei;
        return (int)p[(long long)which * E + e];
    } else {
        const int* p = (const int*)ei;
        return p[(long long)which * E + e];
    }
}

// Clamp any value to a guaranteed-finite float (nan -> -3e38).
__device__ __forceinline__ float fin(float x) {
    if (!(x > -3.0e38f)) return -3.0e38f;  // catches nan and -inf
    if (x > 3.0e38f) return 3.0e38f;
    return x;
}

// Detect int64 vs int32 edge_index: sample high dwords of first 4096 slots.
__global__ void detect64_kernel(const unsigned* u, long long n_dwords,
                                int* flag) {
    __shared__ int any;
    if (threadIdx.x == 0) any = 0;
    __syncthreads();
    long long slots = n_dwords / 2;
    long long cap = slots < 4096 ? slots : 4096;
    for (long long i = threadIdx.x; i < cap; i += blockDim.x)
        if (u[2 * i + 1] != 0u) any = 1;  // benign race, monotonic
    __syncthreads();
    if (threadIdx.x == 0) *flag = any ? 0 : 1;
}

__global__ void zero_cnt_kernel(int* cnt, int n) {
    int i = blockIdx.x * blockDim.x + threadIdx.x;
    int stride = gridDim.x * blockDim.x;
    for (; i < n; i += stride) cnt[i] = 0;
}

// Count: EB edges/thread, fire-and-forget atomics (no return dependency).
__global__ __launch_bounds__(256) void count_edges_kernel(
        const void* ei, const int* flag64, int* cnt, long long E, int n) {
    long long base = ((long long)blockIdx.x * blockDim.x + threadIdx.x) * EB;
    int is64 = *flag64;
    int d[EB];
#pragma unroll
    for (int b = 0; b < EB; ++b) {
        long long e = base + b;
        d[b] = (e < E) ? load_idx(ei, E, 1, e, is64) : -1;
    }
#pragma unroll
    for (int b = 0; b < EB; ++b)
        if ((unsigned)d[b] < (unsigned)n) atomicAdd(&cnt[d[b]], 1);
}

// ------------------------------------------------ 3-phase multi-block scan
__global__ __launch_bounds__(SCHUNK) void scan_p1_kernel(
        const int* __restrict__ cnt, int* __restrict__ bsum, int n) {
    __shared__ int sd[SCHUNK];
    int b = blockIdx.x, t = threadIdx.x;
    int i = b * SCHUNK + t;
    sd[t] = (i < n) ? cnt[i] : 0;
    __syncthreads();
    for (int off = SCHUNK / 2; off > 0; off >>= 1) {
        if (t < off) sd[t] += sd[t + off];
        __syncthreads();
    }
    if (t == 0) bsum[b] = sd[0];
}

__global__ __launch_bounds__(SCHUNK) void scan_p2_kernel(
        const int* __restrict__ bsum, int* __restrict__ boff, int nb,
        int* __restrict__ rowstart_n) {
    __shared__ int sd[SCHUNK];
    __shared__ int s_carry;
    int t = threadIdx.x;
    if (t == 0) s_carry = 0;
    __syncthreads();
    int nloop = (nb + SCHUNK - 1) / SCHUNK;
    for (int bi = 0; bi < nloop; ++bi) {
        int i = bi * SCHUNK + t;
        int v = (i < nb) ? bsum[i] : 0;
        sd[t] = v;
        __syncthreads();
        for (int off = 1; off < SCHUNK; off <<= 1) {
            int add = (t >= off) ? sd[t - off] : 0;
            __syncthreads();
            sd[t] += add;
            __syncthreads();
        }
        int carry = s_carry;
        if (i < nb) boff[i] = carry + sd[t] - v;
        __syncthreads();
        if (t == SCHUNK - 1) s_carry = carry + sd[SCHUNK - 1];
        __syncthreads();
    }
    if (t == 0) *rowstart_n = s_carry;  // rowstart[n] = total
}

__global__ __launch_bounds__(SCHUNK) void scan_p3_kernel(
        const int* __restrict__ cnt, const int* __restrict__ boff,
        int* __restrict__ rowstart, int* __restrict__ wcur,
        float* __restrict__ dinv, int n) {
    __shared__ int sd[SCHUNK];
    int b = blockIdx.x, t = threadIdx.x;
    int i = b * SCHUNK + t;
    int v = (i < n) ? cnt[i] : 0;
    sd[t] = v;
    __syncthreads();
    for (int off = 1; off < SCHUNK; off <<= 1) {
        int add = (t >= off) ? sd[t - off] : 0;
        __syncthreads();
        sd[t] += add;
        __syncthreads();
    }
    if (i < n) {
        int excl = boff[b] + sd[t] - v;
        rowstart[i] = excl;
        wcur[i] = excl;
        dinv[i] = rsqrtf((float)(v + 1));
    }
}

// Fill: EB edges/thread; 3 phases (load all, issue all atomics, store all)
// so the 8 atomic round-trips overlap instead of serializing.
__global__ __launch_bounds__(256) void fill_elist_kernel(
        const void* ei, const int* flag64, int* wcur, int* elist, long long E,
        int n) {
    long long base = ((long long)blockIdx.x * blockDim.x + threadIdx.x) * EB;
    int is64 = *flag64;
    int s[EB], d[EB], pos[EB];
#pragma unroll
    for (int b = 0; b < EB; ++b) {
        long long e = base + b;
        if (e < E) {
            s[b] = load_idx(ei, E, 0, e, is64);
            d[b] = load_idx(ei, E, 1, e, is64);
            if ((unsigned)d[b] >= (unsigned)n) d[b] = -1;       // skip
            else if ((unsigned)s[b] >= (unsigned)n) s[b] = d[b]; // safe fallback
        } else {
            d[b] = -1;
        }
    }
#pragma unroll
    for (int b = 0; b < EB; ++b)
        if (d[b] >= 0) pos[b] = atomicAdd(&wcur[d[b]], 1);
#pragma unroll
    for (int b = 0; b < EB; ++b)
        if (d[b] >= 0 && pos[b] >= 0 && pos[b] < (int)E) elist[pos[b]] = s[b];
}

// ------------------------------------------------------------------- GEMM
// Y[r][c] = dinv[r] * sum_k X[r][k] * W[k][c]; also writes fp16 copy Yh.
#define GFMA(cc, xs)                                                           \
    cc.x = fmaf(xs, wv.x, cc.x);                                               \
    cc.y = fmaf(xs, wv.y, cc.y);                                               \
    cc.z = fmaf(xs, wv.z, cc.z);                                               \
    cc.w = fmaf(xs, wv.w, cc.w);

#define GSTORE(cc, j)                                                          \
    {                                                                          \
        int gr = R0 + row0 + (j);                                              \
        if (gr < n) {                                                          \
            float dv = dinv[gr];                                               \
            float4 o;                                                          \
            o.x = dv * cc.x; o.y = dv * cc.y; o.z = dv * cc.z; o.w = dv * cc.w;\
            *(float4*)(Y + (size_t)gr * HDIM + col0) = o;                      \
            union { __half2 h2[2]; float2 f2; } pk;                            \
            pk.h2[0] = __floats2half2_rn(o.x, o.y);                            \
            pk.h2[1] = __floats2half2_rn(o.z, o.w);                            \
            *(float2*)(Yh + (size_t)gr * HDIM + col0) = pk.f2;                 \
        }                                                                      \
    }

__global__ __launch_bounds__(256) void gemm_scaled_kernel(
        const float* __restrict__ X, const float* __restrict__ Wg,
        const float* __restrict__ dinv, float* __restrict__ Y,
        __half* __restrict__ Yh, int n) {
    __shared__ float xT[HDIM][32];
    int R0 = blockIdx.x * 32;
    int t = threadIdx.x;
    {   // stage x tile transposed: xT[k][r] = X[R0+r][k]
        int r = t & 31, kq8 = t >> 5;
        const float* xr = X + (size_t)(R0 + r) * HDIM;
        bool ok = (R0 + r) < n;
#pragma unroll
        for (int p = 0; p < 4; ++p) {
            int kq = kq8 + p * 8;
            float4 xv = ok ? ((const float4*)xr)[kq] : make_float4(0.f, 0.f, 0.f, 0.f);
            xT[kq * 4 + 0][r] = xv.x;
            xT[kq * 4 + 1][r] = xv.y;
            xT[kq * 4 + 2][r] = xv.z;
            xT[kq * 4 + 3][r] = xv.w;
        }
    }
    __syncthreads();
    int w = t >> 6, lane = t & 63;
    int rg = w >> 1, cg = w & 1;
    int rq = lane >> 4, cq = lane & 15;
    int row0 = rg * 16 + rq * 4;
    int col0 = cg * 64 + cq * 4;
    const float* Wp = Wg + col0;
    float4 c0 = make_float4(0.f, 0.f, 0.f, 0.f), c1 = c0, c2 = c0, c3 = c0;
#pragma unroll 4
    for (int k = 0; k < HDIM; ++k) {
        float4 wv = *(const float4*)(Wp + (size_t)k * HDIM);
        float4 xv = *(const float4*)(&xT[k][row0]);
        GFMA(c0, xv.x);
        GFMA(c1, xv.y);
        GFMA(c2, xv.z);
        GFMA(c3, xv.w);
    }
    GSTORE(c0, 0);
    GSTORE(c1, 1);
    GSTORE(c2, 2);
    GSTORE(c3, 3);
}

// ---------------------------------------------------------- shared gather
// Aggregates (self f32 + fp16 neighbor msgs) for node v; returns float2/lane.
__device__ __forceinline__ float2 gather_node(
        const float* __restrict__ Y, const __half* __restrict__ Yh,
        const int* __restrict__ rowstart, const int* __restrict__ elist,
        int v, int lane, int n) {
    float2 a0 = ((const float2*)(Y + (size_t)v * HDIM))[lane];  // self (f32)
    float2 a1 = make_float2(0.f, 0.f), a2 = a1, a3 = a1;
    int i = rowstart[v], e = rowstart[v + 1];
    for (; i + 4 <= e; i += 4) {
        int sA = elist[i], sB = elist[i + 1], sC = elist[i + 2], sD = elist[i + 3];
        if ((unsigned)sA >= (unsigned)n) sA = v;
        if ((unsigned)sB >= (unsigned)n) sB = v;
        if ((unsigned)sC >= (unsigned)n) sC = v;
        if ((unsigned)sD >= (unsigned)n) sD = v;
        float2 mA = __half22float2(((const __half2*)(Yh + (size_t)sA * HDIM))[lane]);
        float2 mB = __half22float2(((const __half2*)(Yh + (size_t)sB * HDIM))[lane]);
        float2 mC = __half22float2(((const __half2*)(Yh + (size_t)sC * HDIM))[lane]);
        float2 mD = __half22float2(((const __half2*)(Yh + (size_t)sD * HDIM))[lane]);
        a0.x += mA.x; a0.y += mA.y;
        a1.x += mB.x; a1.y += mB.y;
        a2.x += mC.x; a2.y += mC.y;
        a3.x += mD.x; a3.y += mD.y;
    }
    for (; i < e; ++i) {
        int s = elist[i];
        if ((unsigned)s >= (unsigned)n) s = v;
        float2 m = __half22float2(((const __half2*)(Yh + (size_t)s * HDIM))[lane]);
        a0.x += m.x; a0.y += m.y;
    }
    return make_float2(a0.x + a1.x + a2.x + a3.x, a0.y + a1.y + a2.y + a3.y);
}

// -------------------------------------------------------------------- pull
// H[v] = relu(bias + dinv[v] * (Y[v] + sum msgs))      (layer 1)
__global__ __launch_bounds__(256) void pull_relu_kernel(
        const float* __restrict__ Y, const __half* __restrict__ Yh,
        const int* __restrict__ rowstart, const int* __restrict__ elist,
        const float* __restrict__ dinv, const float* __restrict__ bias,
        float* __restrict__ H, int n) {
    int v = (int)((blockIdx.x * blockDim.x + threadIdx.x) >> 6);
    int lane = threadIdx.x & 63;
    if (v >= n) return;
    float2 a = gather_node(Y, Yh, rowstart, elist, v, lane, n);
    float dv = dinv[v];
    float2 b = ((const float2*)bias)[lane];
    float hx = fmaxf(fmaf(dv, a.x, b.x), 0.f);
    float hy = fmaxf(fmaf(dv, a.y, b.y), 0.f);
    ((float2*)(H + (size_t)v * HDIM))[lane] = make_float2(hx, hy);
}

// ------------------------------------------- fused pull (layer 2) + heads
#define SENT (-3.0e38f)
#define BFLY(p) \
    p += __shfl_xor(p, 32); p += __shfl_xor(p, 16); p += __shfl_xor(p, 8); \
    p += __shfl_xor(p, 4);  p += __shfl_xor(p, 2);  p += __shfl_xor(p, 1);

__global__ __launch_bounds__(256) void pull_heads_kernel(
        const float* __restrict__ Y, const __half* __restrict__ Yh,
        const int* __restrict__ rowstart, const int* __restrict__ elist,
        const float* __restrict__ dinv, const float* __restrict__ bias,
        const float* __restrict__ Wdet, const float* __restrict__ bdet,
        const float* __restrict__ Wund, const float* __restrict__ bund,
        const float* __restrict__ Wroot, const float* __restrict__ broot,
        float* __restrict__ out, int n) {
    int v = (int)((blockIdx.x * blockDim.x + threadIdx.x) >> 6);
    int lane = threadIdx.x & 63;
    if (v >= n) return;
    float2 a = gather_node(Y, Yh, rowstart, elist, v, lane, n);
    float dv = dinv[v];
    float2 b = ((const float2*)bias)[lane];
    float hx = fmaxf(fmaf(dv, a.x, b.x), 0.f);   // h[2*lane]
    float hy = fmaxf(fmaf(dv, a.y, b.y), 0.f);   // h[2*lane+1]

    // per-lane head partials: rows 2l,2l+1 of each weight matrix
    float4 wd  = ((const float4*)Wdet)[lane];         // [2l][0],[2l][1],[2l+1][0],[2l+1][1]
    float4 wu  = ((const float4*)Wund)[lane];
    float4 wr0 = ((const float4*)Wroot)[2 * lane];     // row 2l
    float4 wr1 = ((const float4*)Wroot)[2 * lane + 1]; // row 2l+1
    float pd0 = hx * wd.x + hy * wd.z;
    float pd1 = hx * wd.y + hy * wd.w;
    float pu0 = hx * wu.x + hy * wu.z;
    float pu1 = hx * wu.y + hy * wu.w;
    float pr0 = hx * wr0.x + hy * wr1.x;
    float pr1 = hx * wr0.y + hy * wr1.y;
    float pr2 = hx * wr0.z + hy * wr1.z;
    float pr3 = hx * wr0.w + hy * wr1.w;
    BFLY(pd0); BFLY(pd1); BFLY(pu0); BFLY(pu1);
    BFLY(pr0); BFLY(pr1); BFLY(pr2); BFLY(pr3);

    if (lane == 0) {
        float d0 = pd0 + bdet[0], d1 = pd1 + bdet[1];
        float u0 = pu0 + bund[0], u1 = pu1 + bund[1];
        float r0 = pr0 + broot[0], r1 = pr1 + broot[1];
        float r2 = pr2 + broot[2], r3 = pr3 + broot[3];
        float m = fmaxf(d0, d1);
        float lse = m + logf(expf(d0 - m) + expf(d1 - m));
        out[(size_t)v * 2 + 0] = fin(d0 - lse);
        out[(size_t)v * 2 + 1] = fin(d1 - lse);
        float* ro = out + 2 * (size_t)n + (size_t)v * 5;
        if (d1 > d0) {  // argmax == 1 (tie -> index 0 -> false)
            float mm = fmaxf(fmaxf(r0, r1), fmaxf(r2, r3));
            float l2 = mm + logf(expf(r0 - mm) + expf(r1 - mm) +
                                 expf(r2 - mm) + expf(r3 - mm));
            ro[0] = SENT;  // reference: -inf (finite sentinel, inf-inf=nan)
            ro[1] = fin(r0 - l2);
            ro[2] = fin(r1 - l2);
            ro[3] = fin(r2 - l2);
            ro[4] = fin(r3 - l2);
        } else {
            float mm = fmaxf(u0, u1);
            float l2 = mm + logf(expf(u0 - mm) + expf(u1 - mm));
            ro[0] = fin(u0 - l2);
            ro[1] = fin(u1 - l2);
            ro[2] = SENT;
            ro[3] = SENT;
            ro[4] = SENT;
        }
    }
}

__global__ void ws_too_small_kernel(float* out, int n) {
    int i = blockIdx.x * blockDim.x + threadIdx.x;
    if (i < n) out[i] = -12345.0f;  // sentinel: workspace was insufficient
}

// ----------------------------------------------------------------- launch
extern "C" void kernel_launch(void* const* d_in, const int* in_sizes, int n_in,
                              void* d_out, int out_size, void* d_ws,
                              size_t ws_size, hipStream_t stream) {
    const float* x     = (const float*)d_in[0];
    const void*  ei    = d_in[1];
    const float* W1    = (const float*)d_in[2];
    const float* b1    = (const float*)d_in[3];
    const float* W2    = (const float*)d_in[4];
    const float* b2    = (const float*)d_in[5];
    const float* Wdet  = (const float*)d_in[6];
    const float* bdet  = (const float*)d_in[7];
    const float* Wund  = (const float*)d_in[8];
    const float* bund  = (const float*)d_in[9];
    const float* Wroot = (const float*)d_in[10];
    const float* broot = (const float*)d_in[11];
    int N = in_sizes[0] / HDIM;       // 50000
    long long E = in_sizes[1] / 2;    // 800000
    float* out = (float*)d_out;
    int nb = (N + SCHUNK - 1) / SCHUNK;

    // workspace carve (256B aligned)
    size_t off = 0;
    auto carve = [&](size_t bytes) -> void* {
        void* p = (char*)d_ws + off;
        off += (bytes + 255) & ~(size_t)255;
        return p;
    };
    float*  A        = (float*)carve((size_t)N * HDIM * 4);
    float*  B        = (float*)carve((size_t)N * HDIM * 4);
    __half* Ah       = (__half*)carve((size_t)N * HDIM * 2);
    float*  dinv     = (float*)carve((size_t)N * 4);
    int*    cnt      = (int*)carve((size_t)N * 4);
    int*    rowstart = (int*)carve((size_t)(N + 1) * 4);
    int*    wcur     = (int*)carve((size_t)N * 4);
    int*    elist    = (int*)carve((size_t)E * 4);
    int*    bsum     = (int*)carve((size_t)nb * 4);
    int*    boff     = (int*)carve((size_t)nb * 4);
    int*    flag64   = (int*)carve(256);

    if (off > ws_size) {
        ws_too_small_kernel<<<(out_size + 255) / 256, 256, 0, stream>>>(out, out_size);
        return;
    }

    long long ethreads = (E + EB - 1) / EB;
    int egrid = (int)((ethreads + 255) / 256);

    // CSR build
    detect64_kernel<<<1, 256, 0, stream>>>((const unsigned*)ei,
                                           (long long)in_sizes[1], flag64);
    zero_cnt_kernel<<<256, 256, 0, stream>>>(cnt, N);
    count_edges_kernel<<<egrid, 256, 0, stream>>>(ei, flag64, cnt, E, N);
    scan_p1_kernel<<<nb, SCHUNK, 0, stream>>>(cnt, bsum, N);
    scan_p2_kernel<<<1, SCHUNK, 0, stream>>>(bsum, boff, nb, rowstart + N);
    scan_p3_kernel<<<nb, SCHUNK, 0, stream>>>(cnt, boff, rowstart, wcur, dinv, N);
    fill_elist_kernel<<<egrid, 256, 0, stream>>>(ei, flag64, wcur, elist, E, N);

    int gemm_grid = (N + 31) / 32;
    int pull_grid = (N + 3) / 4;      // 4 waves (nodes) per 256-thread block

    // layer 1: A,Ah = dinv * (x @ W1);  B = relu(b1 + dinv*(self + gather))
    gemm_scaled_kernel<<<gemm_grid, 256, 0, stream>>>(x, W1, dinv, A, Ah, N);
    pull_relu_kernel<<<pull_grid, 256, 0, stream>>>(A, Ah, rowstart, elist,
                                                    dinv, b1, B, N);
    // layer 2: A,Ah = dinv * (B @ W2); fused pull + heads -> out
    gemm_scaled_kernel<<<gemm_grid, 256, 0, stream>>>(B, W2, dinv, A, Ah, N);
    pull_heads_kernel<<<pull_grid, 256, 0, stream>>>(A, Ah, rowstart, elist,
                                                     dinv, b2, Wdet, bdet,
                                                     Wund, bund, Wroot, broot,
                                                     out, N);
}

// Round 6
// 256.708 us; speedup vs baseline: 1.5079x; 1.0118x over previous
//
#include <hip/hip_runtime.h>
#include <hip/hip_fp16.h>
#include <math.h>

#define HDIM 128
#define SCHUNK 256
#define EB 8  // edges per thread in count/fill

// ---------------------------------------------------------------- utilities
__device__ __forceinline__ int load_idx(const void* ei, long long E, int which,
                                        long long e, int is64) {
    if (is64) {
        const long long* p = (const long long*)ei;
        return (int)p[(long long)which * E + e];
    } else {
        const int* p = (const int*)ei;
        return p[(long long)which * E + e];
    }
}

// Clamp any value to a guaranteed-finite float (nan -> -3e38).
__device__ __forceinline__ float fin(float x) {
    if (!(x > -3.0e38f)) return -3.0e38f;  // catches nan and -inf
    if (x > 3.0e38f) return 3.0e38f;
    return x;
}

// Detect int64 vs int32 edge_index: sample high dwords of first 4096 slots.
__global__ void detect64_kernel(const unsigned* u, long long n_dwords,
                                int* flag) {
    __shared__ int any;
    if (threadIdx.x == 0) any = 0;
    __syncthreads();
    long long slots = n_dwords / 2;
    long long cap = slots < 4096 ? slots : 4096;
    for (long long i = threadIdx.x; i < cap; i += blockDim.x)
        if (u[2 * i + 1] != 0u) any = 1;  // benign race, monotonic
    __syncthreads();
    if (threadIdx.x == 0) *flag = any ? 0 : 1;
}

__global__ void zero_cnt_kernel(int* cnt, int n) {
    int i = blockIdx.x * blockDim.x + threadIdx.x;
    int stride = gridDim.x * blockDim.x;
    for (; i < n; i += stride) cnt[i] = 0;
}

// Count: EB edges/thread, fire-and-forget atomics (no return dependency).
__global__ __launch_bounds__(256) void count_edges_kernel(
        const void* ei, const int* flag64, int* cnt, long long E, int n) {
    long long base = ((long long)blockIdx.x * blockDim.x + threadIdx.x) * EB;
    int is64 = *flag64;
    int d[EB];
#pragma unroll
    for (int b = 0; b < EB; ++b) {
        long long e = base + b;
        d[b] = (e < E) ? load_idx(ei, E, 1, e, is64) : -1;
    }
#pragma unroll
    for (int b = 0; b < EB; ++b)
        if ((unsigned)d[b] < (unsigned)n) atomicAdd(&cnt[d[b]], 1);
}

// ------------------------------------------------ 3-phase multi-block scan
__global__ __launch_bounds__(SCHUNK) void scan_p1_kernel(
        const int* __restrict__ cnt, int* __restrict__ bsum, int n) {
    __shared__ int sd[SCHUNK];
    int b = blockIdx.x, t = threadIdx.x;
    int i = b * SCHUNK + t;
    sd[t] = (i < n) ? cnt[i] : 0;
    __syncthreads();
    for (int off = SCHUNK / 2; off > 0; off >>= 1) {
        if (t < off) sd[t] += sd[t + off];
        __syncthreads();
    }
    if (t == 0) bsum[b] = sd[0];
}

__global__ __launch_bounds__(SCHUNK) void scan_p2_kernel(
        const int* __restrict__ bsum, int* __restrict__ boff, int nb,
        int* __restrict__ rowstart_n) {
    __shared__ int sd[SCHUNK];
    __shared__ int s_carry;
    int t = threadIdx.x;
    if (t == 0) s_carry = 0;
    __syncthreads();
    int nloop = (nb + SCHUNK - 1) / SCHUNK;
    for (int bi = 0; bi < nloop; ++bi) {
        int i = bi * SCHUNK + t;
        int v = (i < nb) ? bsum[i] : 0;
        sd[t] = v;
        __syncthreads();
        for (int off = 1; off < SCHUNK; off <<= 1) {
            int add = (t >= off) ? sd[t - off] : 0;
            __syncthreads();
            sd[t] += add;
            __syncthreads();
        }
        int carry = s_carry;
        if (i < nb) boff[i] = carry + sd[t] - v;
        __syncthreads();
        if (t == SCHUNK - 1) s_carry = carry + sd[SCHUNK - 1];
        __syncthreads();
    }
    if (t == 0) *rowstart_n = s_carry;  // rowstart[n] = total
}

__global__ __launch_bounds__(SCHUNK) void scan_p3_kernel(
        const int* __restrict__ cnt, const int* __restrict__ boff,
        int* __restrict__ rowstart, int* __restrict__ wcur,
        float* __restrict__ dinv, int n) {
    __shared__ int sd[SCHUNK];
    int b = blockIdx.x, t = threadIdx.x;
    int i = b * SCHUNK + t;
    int v = (i < n) ? cnt[i] : 0;
    sd[t] = v;
    __syncthreads();
    for (int off = 1; off < SCHUNK; off <<= 1) {
        int add = (t >= off) ? sd[t - off] : 0;
        __syncthreads();
        sd[t] += add;
        __syncthreads();
    }
    if (i < n) {
        int excl = boff[b] + sd[t] - v;
        rowstart[i] = excl;
        wcur[i] = excl;
        dinv[i] = rsqrtf((float)(v + 1));
    }
}

// Fill: EB edges/thread; stores BYTE OFFSET (s * 256) of the source row.
// Every slot of every [rowstart[d], rowstart[d+1]) range is written exactly
// once per call with a validated s < n, so gather needs no per-edge guards.
__global__ __launch_bounds__(256) void fill_elist_kernel(
        const void* ei, const int* flag64, int* wcur, unsigned* selist,
        long long E, int n) {
    long long base = ((long long)blockIdx.x * blockDim.x + threadIdx.x) * EB;
    int is64 = *flag64;
    int s[EB], d[EB], pos[EB];
#pragma unroll
    for (int b = 0; b < EB; ++b) {
        long long e = base + b;
        if (e < E) {
            s[b] = load_idx(ei, E, 0, e, is64);
            d[b] = load_idx(ei, E, 1, e, is64);
            if ((unsigned)d[b] >= (unsigned)n) d[b] = -1;       // skip
            else if ((unsigned)s[b] >= (unsigned)n) s[b] = d[b]; // safe fallback
        } else {
            d[b] = -1;
        }
    }
#pragma unroll
    for (int b = 0; b < EB; ++b)
        if (d[b] >= 0) pos[b] = atomicAdd(&wcur[d[b]], 1);
#pragma unroll
    for (int b = 0; b < EB; ++b)
        if (d[b] >= 0 && pos[b] >= 0 && pos[b] < (int)E)
            selist[pos[b]] = (unsigned)s[b] << 8;  // byte offset into Yh
}

// ------------------------------------------------------------------- GEMM
// Y[r][c] = dinv[r] * sum_k X[r][k] * W[k][c]; also writes fp16 copy Yh.
#define GFMA(cc, xs)                                                           \
    cc.x = fmaf(xs, wv.x, cc.x);                                               \
    cc.y = fmaf(xs, wv.y, cc.y);                                               \
    cc.z = fmaf(xs, wv.z, cc.z);                                               \
    cc.w = fmaf(xs, wv.w, cc.w);

#define GSTORE(cc, j)                                                          \
    {                                                                          \
        int gr = R0 + row0 + (j);                                              \
        if (gr < n) {                                                          \
            float dv = dinv[gr];                                               \
            float4 o;                                                          \
            o.x = dv * cc.x; o.y = dv * cc.y; o.z = dv * cc.z; o.w = dv * cc.w;\
            *(float4*)(Y + (size_t)gr * HDIM + col0) = o;                      \
            union { __half2 h2[2]; float2 f2; } pk;                            \
            pk.h2[0] = __floats2half2_rn(o.x, o.y);                            \
            pk.h2[1] = __floats2half2_rn(o.z, o.w);                            \
            *(float2*)(Yh + (size_t)gr * HDIM + col0) = pk.f2;                 \
        }                                                                      \
    }

__global__ __launch_bounds__(256) void gemm_scaled_kernel(
        const float* __restrict__ X, const float* __restrict__ Wg,
        const float* __restrict__ dinv, float* __restrict__ Y,
        __half* __restrict__ Yh, int n) {
    __shared__ float xT[HDIM][32];
    int R0 = blockIdx.x * 32;
    int t = threadIdx.x;
    {   // stage x tile transposed: xT[k][r] = X[R0+r][k]
        int r = t & 31, kq8 = t >> 5;
        const float* xr = X + (size_t)(R0 + r) * HDIM;
        bool ok = (R0 + r) < n;
#pragma unroll
        for (int p = 0; p < 4; ++p) {
            int kq = kq8 + p * 8;
            float4 xv = ok ? ((const float4*)xr)[kq] : make_float4(0.f, 0.f, 0.f, 0.f);
            xT[kq * 4 + 0][r] = xv.x;
            xT[kq * 4 + 1][r] = xv.y;
            xT[kq * 4 + 2][r] = xv.z;
            xT[kq * 4 + 3][r] = xv.w;
        }
    }
    __syncthreads();
    int w = t >> 6, lane = t & 63;
    int rg = w >> 1, cg = w & 1;
    int rq = lane >> 4, cq = lane & 15;
    int row0 = rg * 16 + rq * 4;
    int col0 = cg * 64 + cq * 4;
    const float* Wp = Wg + col0;
    float4 c0 = make_float4(0.f, 0.f, 0.f, 0.f), c1 = c0, c2 = c0, c3 = c0;
#pragma unroll 4
    for (int k = 0; k < HDIM; ++k) {
        float4 wv = *(const float4*)(Wp + (size_t)k * HDIM);
        float4 xv = *(const float4*)(&xT[k][row0]);
        GFMA(c0, xv.x);
        GFMA(c1, xv.y);
        GFMA(c2, xv.z);
        GFMA(c3, xv.w);
    }
    GSTORE(c0, 0);
    GSTORE(c1, 1);
    GSTORE(c2, 2);
    GSTORE(c3, 3);
}

// ---------------------------------------------------------- shared gather
// Aggregates (self f32 + fp16 neighbor msgs) for node v; returns float2/lane.
// Groups of 4 edges are summed pairwise in fp16 (v_pk_add_f16, depth 2),
// converted once to f32 and accumulated. selist entries are byte offsets.
__device__ __forceinline__ float2 gather_node(
        const float* __restrict__ Y, const __half* __restrict__ Yh,
        const int* __restrict__ rowstart, const unsigned* __restrict__ selist,
        int v, int lane) {
    const char* Yhb = (const char*)Yh;
    unsigned loff = (unsigned)lane * 4u;
    float2 acc = ((const float2*)(Y + (size_t)v * HDIM))[lane];  // self (f32)
    int i = rowstart[v], e = rowstart[v + 1];
    for (; i + 4 <= e; i += 4) {
        unsigned oA = selist[i] + loff;
        unsigned oB = selist[i + 1] + loff;
        unsigned oC = selist[i + 2] + loff;
        unsigned oD = selist[i + 3] + loff;
        __half2 mA = *(const __half2*)(Yhb + oA);
        __half2 mB = *(const __half2*)(Yhb + oB);
        __half2 mC = *(const __half2*)(Yhb + oC);
        __half2 mD = *(const __half2*)(Yhb + oD);
        __half2 s = __hadd2(__hadd2(mA, mB), __hadd2(mC, mD));
        float2 f = __half22float2(s);
        acc.x += f.x; acc.y += f.y;
    }
    for (; i < e; ++i) {
        unsigned o = selist[i] + loff;
        float2 f = __half22float2(*(const __half2*)(Yhb + o));
        acc.x += f.x; acc.y += f.y;
    }
    return acc;
}

// -------------------------------------------------------------------- pull
// H[v] = relu(bias + dinv[v] * (Y[v] + sum msgs))      (layer 1)
__global__ __launch_bounds__(256) void pull_relu_kernel(
        const float* __restrict__ Y, const __half* __restrict__ Yh,
        const int* __restrict__ rowstart, const unsigned* __restrict__ selist,
        const float* __restrict__ dinv, const float* __restrict__ bias,
        float* __restrict__ H, int n) {
    int v = (int)((blockIdx.x * blockDim.x + threadIdx.x) >> 6);
    int lane = threadIdx.x & 63;
    if (v >= n) return;
    float2 a = gather_node(Y, Yh, rowstart, selist, v, lane);
    float dv = dinv[v];
    float2 b = ((const float2*)bias)[lane];
    float hx = fmaxf(fmaf(dv, a.x, b.x), 0.f);
    float hy = fmaxf(fmaf(dv, a.y, b.y), 0.f);
    ((float2*)(H + (size_t)v * HDIM))[lane] = make_float2(hx, hy);
}

// ------------------------------------------- fused pull (layer 2) + heads
#define SENT (-3.0e38f)
#define BFLY(p) \
    p += __shfl_xor(p, 32); p += __shfl_xor(p, 16); p += __shfl_xor(p, 8); \
    p += __shfl_xor(p, 4);  p += __shfl_xor(p, 2);  p += __shfl_xor(p, 1);

__global__ __launch_bounds__(256) void pull_heads_kernel(
        const float* __restrict__ Y, const __half* __restrict__ Yh,
        const int* __restrict__ rowstart, const unsigned* __restrict__ selist,
        const float* __restrict__ dinv, const float* __restrict__ bias,
        const float* __restrict__ Wdet, const float* __restrict__ bdet,
        const float* __restrict__ Wund, const float* __restrict__ bund,
        const float* __restrict__ Wroot, const float* __restrict__ broot,
        float* __restrict__ out, int n) {
    int v = (int)((blockIdx.x * blockDim.x + threadIdx.x) >> 6);
    int lane = threadIdx.x & 63;
    if (v >= n) return;
    float2 a = gather_node(Y, Yh, rowstart, selist, v, lane);
    float dv = dinv[v];
    float2 b = ((const float2*)bias)[lane];
    float hx = fmaxf(fmaf(dv, a.x, b.x), 0.f);   // h[2*lane]
    float hy = fmaxf(fmaf(dv, a.y, b.y), 0.f);   // h[2*lane+1]

    // per-lane head partials: rows 2l,2l+1 of each weight matrix
    float4 wd  = ((const float4*)Wdet)[lane];         // [2l][0],[2l][1],[2l+1][0],[2l+1][1]
    float4 wu  = ((const float4*)Wund)[lane];
    float4 wr0 = ((const float4*)Wroot)[2 * lane];     // row 2l
    float4 wr1 = ((const float4*)Wroot)[2 * lane + 1]; // row 2l+1
    float pd0 = hx * wd.x + hy * wd.z;
    float pd1 = hx * wd.y + hy * wd.w;
    float pu0 = hx * wu.x + hy * wu.z;
    float pu1 = hx * wu.y + hy * wu.w;
    float pr0 = hx * wr0.x + hy * wr1.x;
    float pr1 = hx * wr0.y + hy * wr1.y;
    float pr2 = hx * wr0.z + hy * wr1.z;
    float pr3 = hx * wr0.w + hy * wr1.w;
    BFLY(pd0); BFLY(pd1); BFLY(pu0); BFLY(pu1);
    BFLY(pr0); BFLY(pr1); BFLY(pr2); BFLY(pr3);

    if (lane == 0) {
        float d0 = pd0 + bdet[0], d1 = pd1 + bdet[1];
        float u0 = pu0 + bund[0], u1 = pu1 + bund[1];
        float r0 = pr0 + broot[0], r1 = pr1 + broot[1];
        float r2 = pr2 + broot[2], r3 = pr3 + broot[3];
        float m = fmaxf(d0, d1);
        float lse = m + logf(expf(d0 - m) + expf(d1 - m));
        out[(size_t)v * 2 + 0] = fin(d0 - lse);
        out[(size_t)v * 2 + 1] = fin(d1 - lse);
        float* ro = out + 2 * (size_t)n + (size_t)v * 5;
        if (d1 > d0) {  // argmax == 1 (tie -> index 0 -> false)
            float mm = fmaxf(fmaxf(r0, r1), fmaxf(r2, r3));
            float l2 = mm + logf(expf(r0 - mm) + expf(r1 - mm) +
                                 expf(r2 - mm) + expf(r3 - mm));
            ro[0] = SENT;  // reference: -inf (finite sentinel, inf-inf=nan)
            ro[1] = fin(r0 - l2);
            ro[2] = fin(r1 - l2);
            ro[3] = fin(r2 - l2);
            ro[4] = fin(r3 - l2);
        } else {
            float mm = fmaxf(u0, u1);
            float l2 = mm + logf(expf(u0 - mm) + expf(u1 - mm));
            ro[0] = fin(u0 - l2);
            ro[1] = fin(u1 - l2);
            ro[2] = SENT;
            ro[3] = SENT;
            ro[4] = SENT;
        }
    }
}

__global__ void ws_too_small_kernel(float* out, int n) {
    int i = blockIdx.x * blockDim.x + threadIdx.x;
    if (i < n) out[i] = -12345.0f;  // sentinel: workspace was insufficient
}

// ----------------------------------------------------------------- launch
extern "C" void kernel_launch(void* const* d_in, const int* in_sizes, int n_in,
                              void* d_out, int out_size, void* d_ws,
                              size_t ws_size, hipStream_t stream) {
    const float* x     = (const float*)d_in[0];
    const void*  ei    = d_in[1];
    const float* W1    = (const float*)d_in[2];
    const float* b1    = (const float*)d_in[3];
    const float* W2    = (const float*)d_in[4];
    const float* b2    = (const float*)d_in[5];
    const float* Wdet  = (const float*)d_in[6];
    const float* bdet  = (const float*)d_in[7];
    const float* Wund  = (const float*)d_in[8];
    const float* bund  = (const float*)d_in[9];
    const float* Wroot = (const float*)d_in[10];
    const float* broot = (const float*)d_in[11];
    int N = in_sizes[0] / HDIM;       // 50000
    long long E = in_sizes[1] / 2;    // 800000
    float* out = (float*)d_out;
    int nb = (N + SCHUNK - 1) / SCHUNK;

    // workspace carve (256B aligned)
    size_t off = 0;
    auto carve = [&](size_t bytes) -> void* {
        void* p = (char*)d_ws + off;
        off += (bytes + 255) & ~(size_t)255;
        return p;
    };
    float*    A        = (float*)carve((size_t)N * HDIM * 4);
    float*    B        = (float*)carve((size_t)N * HDIM * 4);
    __half*   Ah       = (__half*)carve((size_t)N * HDIM * 2);
    float*    dinv     = (float*)carve((size_t)N * 4);
    int*      cnt      = (int*)carve((size_t)N * 4);
    int*      rowstart = (int*)carve((size_t)(N + 1) * 4);
    int*      wcur     = (int*)carve((size_t)N * 4);
    unsigned* selist   = (unsigned*)carve((size_t)E * 4);
    int*      bsum     = (int*)carve((size_t)nb * 4);
    int*      boff     = (int*)carve((size_t)nb * 4);
    int*      flag64   = (int*)carve(256);

    if (off > ws_size) {
        ws_too_small_kernel<<<(out_size + 255) / 256, 256, 0, stream>>>(out, out_size);
        return;
    }

    long long ethreads = (E + EB - 1) / EB;
    int egrid = (int)((ethreads + 255) / 256);

    // CSR build
    detect64_kernel<<<1, 256, 0, stream>>>((const unsigned*)ei,
                                           (long long)in_sizes[1], flag64);
    zero_cnt_kernel<<<256, 256, 0, stream>>>(cnt, N);
    count_edges_kernel<<<egrid, 256, 0, stream>>>(ei, flag64, cnt, E, N);
    scan_p1_kernel<<<nb, SCHUNK, 0, stream>>>(cnt, bsum, N);
    scan_p2_kernel<<<1, SCHUNK, 0, stream>>>(bsum, boff, nb, rowstart + N);
    scan_p3_kernel<<<nb, SCHUNK, 0, stream>>>(cnt, boff, rowstart, wcur, dinv, N);
    fill_elist_kernel<<<egrid, 256, 0, stream>>>(ei, flag64, wcur, selist, E, N);

    int gemm_grid = (N + 31) / 32;
    int pull_grid = (N + 3) / 4;      // 4 waves (nodes) per 256-thread block

    // layer 1: A,Ah = dinv * (x @ W1);  B = relu(b1 + dinv*(self + gather))
    gemm_scaled_kernel<<<gemm_grid, 256, 0, stream>>>(x, W1, dinv, A, Ah, N);
    pull_relu_kernel<<<pull_grid, 256, 0, stream>>>(A, Ah, rowstart, selist,
                                                    dinv, b1, B, N);
    // layer 2: A,Ah = dinv * (B @ W2); fused pull + heads -> out
    gemm_scaled_kernel<<<gemm_grid, 256, 0, stream>>>(B, W2, dinv, A, Ah, N);
    pull_heads_kernel<<<pull_grid, 256, 0, stream>>>(A, Ah, rowstart, selist,
                                                     dinv, b2, Wdet, bdet,
                                                     Wund, bund, Wroot, broot,
                                                     out, N);
}

// Round 7
// 244.174 us; speedup vs baseline: 1.5853x; 1.0513x over previous
//
#include <hip/hip_runtime.h>
#include <hip/hip_fp16.h>
#include <math.h>

#define HDIM 128
#define SCHUNK 256
#define EB 4  // edges per thread in count

// ---------------------------------------------------------------- utilities
__device__ __forceinline__ int load_idx(const void* ei, long long E, int which,
                                        long long e, int is64) {
    if (is64) {
        const long long* p = (const long long*)ei;
        return (int)p[(long long)which * E + e];
    } else {
        const int* p = (const int*)ei;
        return p[(long long)which * E + e];
    }
}

// Clamp any value to a guaranteed-finite float (nan -> -3e38).
__device__ __forceinline__ float fin(float x) {
    if (!(x > -3.0e38f)) return -3.0e38f;  // catches nan and -inf
    if (x > 3.0e38f) return 3.0e38f;
    return x;
}

// Detect int64 vs int32 edge_index: sample high dwords of first 4096 slots.
__global__ void detect64_kernel(const unsigned* u, long long n_dwords,
                                int* flag) {
    __shared__ int any;
    if (threadIdx.x == 0) any = 0;
    __syncthreads();
    long long slots = n_dwords / 2;
    long long cap = slots < 4096 ? slots : 4096;
    for (long long i = threadIdx.x; i < cap; i += blockDim.x)
        if (u[2 * i + 1] != 0u) any = 1;  // benign race, monotonic
    __syncthreads();
    if (threadIdx.x == 0) *flag = any ? 0 : 1;
}

__global__ void zero_cnt_kernel(int* cnt, int n) {
    int i = blockIdx.x * blockDim.x + threadIdx.x;
    int stride = gridDim.x * blockDim.x;
    for (; i < n; i += stride) cnt[i] = 0;
}

// Count: EB edges/thread, fire-and-forget atomics (no return dependency).
__global__ __launch_bounds__(256) void count_edges_kernel(
        const void* ei, const int* flag64, int* cnt, long long E, int n) {
    long long base = ((long long)blockIdx.x * blockDim.x + threadIdx.x) * EB;
    int is64 = *flag64;
    int d[EB];
#pragma unroll
    for (int b = 0; b < EB; ++b) {
        long long e = base + b;
        d[b] = (e < E) ? load_idx(ei, E, 1, e, is64) : -1;
    }
#pragma unroll
    for (int b = 0; b < EB; ++b)
        if ((unsigned)d[b] < (unsigned)n) atomicAdd(&cnt[d[b]], 1);
}

// ------------------------------------------------ 3-phase multi-block scan
__global__ __launch_bounds__(SCHUNK) void scan_p1_kernel(
        const int* __restrict__ cnt, int* __restrict__ bsum, int n) {
    __shared__ int sd[SCHUNK];
    int b = blockIdx.x, t = threadIdx.x;
    int i = b * SCHUNK + t;
    sd[t] = (i < n) ? cnt[i] : 0;
    __syncthreads();
    for (int off = SCHUNK / 2; off > 0; off >>= 1) {
        if (t < off) sd[t] += sd[t + off];
        __syncthreads();
    }
    if (t == 0) bsum[b] = sd[0];
}

__global__ __launch_bounds__(SCHUNK) void scan_p2_kernel(
        const int* __restrict__ bsum, int* __restrict__ boff, int nb,
        int* __restrict__ rowstart_n) {
    __shared__ int sd[SCHUNK];
    __shared__ int s_carry;
    int t = threadIdx.x;
    if (t == 0) s_carry = 0;
    __syncthreads();
    int nloop = (nb + SCHUNK - 1) / SCHUNK;
    for (int bi = 0; bi < nloop; ++bi) {
        int i = bi * SCHUNK + t;
        int v = (i < nb) ? bsum[i] : 0;
        sd[t] = v;
        __syncthreads();
        for (int off = 1; off < SCHUNK; off <<= 1) {
            int add = (t >= off) ? sd[t - off] : 0;
            __syncthreads();
            sd[t] += add;
            __syncthreads();
        }
        int carry = s_carry;
        if (i < nb) boff[i] = carry + sd[t] - v;
        __syncthreads();
        if (t == SCHUNK - 1) s_carry = carry + sd[SCHUNK - 1];
        __syncthreads();
    }
    if (t == 0) *rowstart_n = s_carry;  // rowstart[n] = total
}

__global__ __launch_bounds__(SCHUNK) void scan_p3_kernel(
        const int* __restrict__ cnt, const int* __restrict__ boff,
        int* __restrict__ rowstart, int* __restrict__ wcur,
        float* __restrict__ dinv, int n) {
    __shared__ int sd[SCHUNK];
    int b = blockIdx.x, t = threadIdx.x;
    int i = b * SCHUNK + t;
    int v = (i < n) ? cnt[i] : 0;
    sd[t] = v;
    __syncthreads();
    for (int off = 1; off < SCHUNK; off <<= 1) {
        int add = (t >= off) ? sd[t - off] : 0;
        __syncthreads();
        sd[t] += add;
        __syncthreads();
    }
    if (i < n) {
        int excl = boff[b] + sd[t] - v;
        rowstart[i] = excl;
        wcur[i] = excl;
        dinv[i] = rsqrtf((float)(v + 1));
    }
}

// --------------------------- CSR fill, split for full occupancy both sides
// Phase A: 1 edge/thread; atomic slot grab, COALESCED posbuf store.
__global__ __launch_bounds__(256) void pos_edges_kernel(
        const void* ei, const int* flag64, int* wcur, int* posbuf,
        long long E, int n) {
    long long e = (long long)blockIdx.x * blockDim.x + threadIdx.x;
    if (e >= E) return;
    int is64 = *flag64;
    int d = load_idx(ei, E, 1, e, is64);
    int pos = -1;
    if ((unsigned)d < (unsigned)n) pos = atomicAdd(&wcur[d], 1);
    posbuf[e] = pos;
}

// Phase B: 1 edge/thread; no atomics, scattered 4B store.
// Every slot of every [rowstart[d], rowstart[d+1]) range is written exactly
// once per call with a validated s < n, so gather needs no per-edge guards.
__global__ __launch_bounds__(256) void scatter_elist_kernel(
        const void* ei, const int* flag64, const int* __restrict__ posbuf,
        unsigned* __restrict__ selist, long long E, int n) {
    long long e = (long long)blockIdx.x * blockDim.x + threadIdx.x;
    if (e >= E) return;
    int pos = posbuf[e];
    if (pos < 0 || pos >= (int)E) return;
    int is64 = *flag64;
    int s = load_idx(ei, E, 0, e, is64);
    if ((unsigned)s >= (unsigned)n) s = load_idx(ei, E, 1, e, is64);  // = d, valid
    selist[pos] = (unsigned)s << 8;  // byte offset into Yh
}

// ------------------------------------------------------------------- GEMM
// Yh[r][c] = fp16( dinv[r] * sum_k X[r][k] * W[k][c] )   (fp16 table only)
#define GFMA(cc, xs)                                                           \
    cc.x = fmaf(xs, wv.x, cc.x);                                               \
    cc.y = fmaf(xs, wv.y, cc.y);                                               \
    cc.z = fmaf(xs, wv.z, cc.z);                                               \
    cc.w = fmaf(xs, wv.w, cc.w);

#define GSTORE(cc, j)                                                          \
    {                                                                          \
        int gr = R0 + row0 + (j);                                              \
        if (gr < n) {                                                          \
            float dv = dinv[gr];                                               \
            union { __half2 h2[2]; float2 f2; } pk;                            \
            pk.h2[0] = __floats2half2_rn(dv * cc.x, dv * cc.y);                \
            pk.h2[1] = __floats2half2_rn(dv * cc.z, dv * cc.w);                \
            *(float2*)(Yh + (size_t)gr * HDIM + col0) = pk.f2;                 \
        }                                                                      \
    }

__global__ __launch_bounds__(256) void gemm_scaled_kernel(
        const float* __restrict__ X, const float* __restrict__ Wg,
        const float* __restrict__ dinv, __half* __restrict__ Yh, int n) {
    __shared__ float xT[HDIM][32];
    int R0 = blockIdx.x * 32;
    int t = threadIdx.x;
    {   // stage x tile transposed: xT[k][r] = X[R0+r][k]
        int r = t & 31, kq8 = t >> 5;
        const float* xr = X + (size_t)(R0 + r) * HDIM;
        bool ok = (R0 + r) < n;
#pragma unroll
        for (int p = 0; p < 4; ++p) {
            int kq = kq8 + p * 8;
            float4 xv = ok ? ((const float4*)xr)[kq] : make_float4(0.f, 0.f, 0.f, 0.f);
            xT[kq * 4 + 0][r] = xv.x;
            xT[kq * 4 + 1][r] = xv.y;
            xT[kq * 4 + 2][r] = xv.z;
            xT[kq * 4 + 3][r] = xv.w;
        }
    }
    __syncthreads();
    int w = t >> 6, lane = t & 63;
    int rg = w >> 1, cg = w & 1;
    int rq = lane >> 4, cq = lane & 15;
    int row0 = rg * 16 + rq * 4;
    int col0 = cg * 64 + cq * 4;
    const float* Wp = Wg + col0;
    float4 c0 = make_float4(0.f, 0.f, 0.f, 0.f), c1 = c0, c2 = c0, c3 = c0;
#pragma unroll 4
    for (int k = 0; k < HDIM; ++k) {
        float4 wv = *(const float4*)(Wp + (size_t)k * HDIM);
        float4 xv = *(const float4*)(&xT[k][row0]);
        GFMA(c0, xv.x);
        GFMA(c1, xv.y);
        GFMA(c2, xv.z);
        GFMA(c3, xv.w);
    }
    GSTORE(c0, 0);
    GSTORE(c1, 1);
    GSTORE(c2, 2);
    GSTORE(c3, 3);
}

// ---------------------------------------------------------- shared gather
// Aggregates self + fp16 neighbor msgs for node v; returns float2/lane.
// Two independent 4-edge groups per iteration -> 8 row loads in flight.
// Each 4-group: depth-2 fp16 tree, converted once to f32 and accumulated.
#define G4(mA, mB, mC, mD, accv)                                               \
    {                                                                          \
        __half2 sH = __hadd2(__hadd2(mA, mB), __hadd2(mC, mD));                \
        float2 fH = __half22float2(sH);                                        \
        accv.x += fH.x; accv.y += fH.y;                                        \
    }

__device__ __forceinline__ float2 gather_node(
        const __half* __restrict__ Yh, const int* __restrict__ rowstart,
        const unsigned* __restrict__ selist, int v, int lane) {
    const char* Yhb = (const char*)Yh;
    unsigned loff = (unsigned)lane * 4u;
    // self term (fp16 table)
    float2 acc = __half22float2(
        *(const __half2*)(Yhb + ((unsigned)v << 8) + loff));
    float2 acc2 = make_float2(0.f, 0.f);
    int i = rowstart[v], e = rowstart[v + 1];
    for (; i + 8 <= e; i += 8) {
        unsigned o0 = selist[i] + loff,     o1 = selist[i + 1] + loff;
        unsigned o2 = selist[i + 2] + loff, o3 = selist[i + 3] + loff;
        unsigned o4 = selist[i + 4] + loff, o5 = selist[i + 5] + loff;
        unsigned o6 = selist[i + 6] + loff, o7 = selist[i + 7] + loff;
        __half2 m0 = *(const __half2*)(Yhb + o0);
        __half2 m1 = *(const __half2*)(Yhb + o1);
        __half2 m2 = *(const __half2*)(Yhb + o2);
        __half2 m3 = *(const __half2*)(Yhb + o3);
        __half2 m4 = *(const __half2*)(Yhb + o4);
        __half2 m5 = *(const __half2*)(Yhb + o5);
        __half2 m6 = *(const __half2*)(Yhb + o6);
        __half2 m7 = *(const __half2*)(Yhb + o7);
        G4(m0, m1, m2, m3, acc);
        G4(m4, m5, m6, m7, acc2);
    }
    for (; i + 4 <= e; i += 4) {
        unsigned o0 = selist[i] + loff,     o1 = selist[i + 1] + loff;
        unsigned o2 = selist[i + 2] + loff, o3 = selist[i + 3] + loff;
        __half2 m0 = *(const __half2*)(Yhb + o0);
        __half2 m1 = *(const __half2*)(Yhb + o1);
        __half2 m2 = *(const __half2*)(Yhb + o2);
        __half2 m3 = *(const __half2*)(Yhb + o3);
        G4(m0, m1, m2, m3, acc);
    }
    for (; i < e; ++i) {
        float2 f = __half22float2(*(const __half2*)(Yhb + selist[i] + loff));
        acc.x += f.x; acc.y += f.y;
    }
    return make_float2(acc.x + acc2.x, acc.y + acc2.y);
}

// -------------------------------------------------------------------- pull
// H[v] = relu(bias + dinv[v] * (self + sum msgs))      (layer 1)
__global__ __launch_bounds__(256) void pull_relu_kernel(
        const __half* __restrict__ Yh, const int* __restrict__ rowstart,
        const unsigned* __restrict__ selist, const float* __restrict__ dinv,
        const float* __restrict__ bias, float* __restrict__ H, int n) {
    int v = (int)((blockIdx.x * blockDim.x + threadIdx.x) >> 6);
    int lane = threadIdx.x & 63;
    if (v >= n) return;
    float2 a = gather_node(Yh, rowstart, selist, v, lane);
    float dv = dinv[v];
    float2 b = ((const float2*)bias)[lane];
    float hx = fmaxf(fmaf(dv, a.x, b.x), 0.f);
    float hy = fmaxf(fmaf(dv, a.y, b.y), 0.f);
    ((float2*)(H + (size_t)v * HDIM))[lane] = make_float2(hx, hy);
}

// ------------------------------------------- fused pull (layer 2) + heads
#define SENT (-3.0e38f)
#define BFLY(p) \
    p += __shfl_xor(p, 32); p += __shfl_xor(p, 16); p += __shfl_xor(p, 8); \
    p += __shfl_xor(p, 4);  p += __shfl_xor(p, 2);  p += __shfl_xor(p, 1);

__global__ __launch_bounds__(256) void pull_heads_kernel(
        const __half* __restrict__ Yh, const int* __restrict__ rowstart,
        const unsigned* __restrict__ selist, const float* __restrict__ dinv,
        const float* __restrict__ bias,
        const float* __restrict__ Wdet, const float* __restrict__ bdet,
        const float* __restrict__ Wund, const float* __restrict__ bund,
        const float* __restrict__ Wroot, const float* __restrict__ broot,
        float* __restrict__ out, int n) {
    int v = (int)((blockIdx.x * blockDim.x + threadIdx.x) >> 6);
    int lane = threadIdx.x & 63;
    if (v >= n) return;
    float2 a = gather_node(Yh, rowstart, selist, v, lane);
    float dv = dinv[v];
    float2 b = ((const float2*)bias)[lane];
    float hx = fmaxf(fmaf(dv, a.x, b.x), 0.f);   // h[2*lane]
    float hy = fmaxf(fmaf(dv, a.y, b.y), 0.f);   // h[2*lane+1]

    // per-lane head partials: rows 2l,2l+1 of each weight matrix
    float4 wd  = ((const float4*)Wdet)[lane];
    float4 wu  = ((const float4*)Wund)[lane];
    float4 wr0 = ((const float4*)Wroot)[2 * lane];
    float4 wr1 = ((const float4*)Wroot)[2 * lane + 1];
    float pd0 = hx * wd.x + hy * wd.z;
    float pd1 = hx * wd.y + hy * wd.w;
    float pu0 = hx * wu.x + hy * wu.z;
    float pu1 = hx * wu.y + hy * wu.w;
    float pr0 = hx * wr0.x + hy * wr1.x;
    float pr1 = hx * wr0.y + hy * wr1.y;
    float pr2 = hx * wr0.z + hy * wr1.z;
    float pr3 = hx * wr0.w + hy * wr1.w;
    BFLY(pd0); BFLY(pd1); BFLY(pu0); BFLY(pu1);
    BFLY(pr0); BFLY(pr1); BFLY(pr2); BFLY(pr3);

    if (lane == 0) {
        float d0 = pd0 + bdet[0], d1 = pd1 + bdet[1];
        float u0 = pu0 + bund[0], u1 = pu1 + bund[1];
        float r0 = pr0 + broot[0], r1 = pr1 + broot[1];
        float r2 = pr2 + broot[2], r3 = pr3 + broot[3];
        float m = fmaxf(d0, d1);
        float lse = m + logf(expf(d0 - m) + expf(d1 - m));
        out[(size_t)v * 2 + 0] = fin(d0 - lse);
        out[(size_t)v * 2 + 1] = fin(d1 - lse);
        float* ro = out + 2 * (size_t)n + (size_t)v * 5;
        if (d1 > d0) {  // argmax == 1 (tie -> index 0 -> false)
            float mm = fmaxf(fmaxf(r0, r1), fmaxf(r2, r3));
            float l2 = mm + logf(expf(r0 - mm) + expf(r1 - mm) +
                                 expf(r2 - mm) + expf(r3 - mm));
            ro[0] = SENT;  // reference: -inf (finite sentinel, inf-inf=nan)
            ro[1] = fin(r0 - l2);
            ro[2] = fin(r1 - l2);
            ro[3] = fin(r2 - l2);
            ro[4] = fin(r3 - l2);
        } else {
            float mm = fmaxf(u0, u1);
            float l2 = mm + logf(expf(u0 - mm) + expf(u1 - mm));
            ro[0] = fin(u0 - l2);
            ro[1] = fin(u1 - l2);
            ro[2] = SENT;
            ro[3] = SENT;
            ro[4] = SENT;
        }
    }
}

__global__ void ws_too_small_kernel(float* out, int n) {
    int i = blockIdx.x * blockDim.x + threadIdx.x;
    if (i < n) out[i] = -12345.0f;  // sentinel: workspace was insufficient
}

// ----------------------------------------------------------------- launch
extern "C" void kernel_launch(void* const* d_in, const int* in_sizes, int n_in,
                              void* d_out, int out_size, void* d_ws,
                              size_t ws_size, hipStream_t stream) {
    const float* x     = (const float*)d_in[0];
    const void*  ei    = d_in[1];
    const float* W1    = (const float*)d_in[2];
    const float* b1    = (const float*)d_in[3];
    const float* W2    = (const float*)d_in[4];
    const float* b2    = (const float*)d_in[5];
    const float* Wdet  = (const float*)d_in[6];
    const float* bdet  = (const float*)d_in[7];
    const float* Wund  = (const float*)d_in[8];
    const float* bund  = (const float*)d_in[9];
    const float* Wroot = (const float*)d_in[10];
    const float* broot = (const float*)d_in[11];
    int N = in_sizes[0] / HDIM;       // 50000
    long long E = in_sizes[1] / 2;    // 800000
    float* out = (float*)d_out;
    int nb = (N + SCHUNK - 1) / SCHUNK;

    // workspace carve (256B aligned)
    size_t off = 0;
    auto carve = [&](size_t bytes) -> void* {
        void* p = (char*)d_ws + off;
        off += (bytes + 255) & ~(size_t)255;
        return p;
    };
    float*    B        = (float*)carve((size_t)N * HDIM * 4);
    __half*   Ah       = (__half*)carve((size_t)N * HDIM * 2);
    float*    dinv     = (float*)carve((size_t)N * 4);
    int*      cnt      = (int*)carve((size_t)N * 4);
    int*      rowstart = (int*)carve((size_t)(N + 1) * 4);
    int*      wcur     = (int*)carve((size_t)N * 4);
    int*      posbuf   = (int*)carve((size_t)E * 4);
    unsigned* selist   = (unsigned*)carve((size_t)E * 4);
    int*      bsum     = (int*)carve((size_t)nb * 4);
    int*      boff     = (int*)carve((size_t)nb * 4);
    int*      flag64   = (int*)carve(256);

    if (off > ws_size) {
        ws_too_small_kernel<<<(out_size + 255) / 256, 256, 0, stream>>>(out, out_size);
        return;
    }

    long long cthreads = (E + EB - 1) / EB;
    int cgrid = (int)((cthreads + 255) / 256);
    int e1grid = (int)((E + 255) / 256);

    // CSR build
    detect64_kernel<<<1, 256, 0, stream>>>((const unsigned*)ei,
                                           (long long)in_sizes[1], flag64);
    zero_cnt_kernel<<<256, 256, 0, stream>>>(cnt, N);
    count_edges_kernel<<<cgrid, 256, 0, stream>>>(ei, flag64, cnt, E, N);
    scan_p1_kernel<<<nb, SCHUNK, 0, stream>>>(cnt, bsum, N);
    scan_p2_kernel<<<1, SCHUNK, 0, stream>>>(bsum, boff, nb, rowstart + N);
    scan_p3_kernel<<<nb, SCHUNK, 0, stream>>>(cnt, boff, rowstart, wcur, dinv, N);
    pos_edges_kernel<<<e1grid, 256, 0, stream>>>(ei, flag64, wcur, posbuf, E, N);
    scatter_elist_kernel<<<e1grid, 256, 0, stream>>>(ei, flag64, posbuf,
                                                     selist, E, N);

    int gemm_grid = (N + 31) / 32;
    int pull_grid = (N + 3) / 4;      // 4 waves (nodes) per 256-thread block

    // layer 1: Ah = fp16(dinv * (x @ W1));  B = relu(b1 + dinv*(self+gather))
    gemm_scaled_kernel<<<gemm_grid, 256, 0, stream>>>(x, W1, dinv, Ah, N);
    pull_relu_kernel<<<pull_grid, 256, 0, stream>>>(Ah, rowstart, selist,
                                                    dinv, b1, B, N);
    // layer 2: Ah = fp16(dinv * (B @ W2)); fused pull + heads -> out
    gemm_scaled_kernel<<<gemm_grid, 256, 0, stream>>>(B, W2, dinv, Ah, N);
    pull_heads_kernel<<<pull_grid, 256, 0, stream>>>(Ah, rowstart, selist,
                                                     dinv, b2, Wdet, bdet,
                                                     Wund, bund, Wroot, broot,
                                                     out, N);
}

// Round 8
// 211.321 us; speedup vs baseline: 1.8318x; 1.1555x over previous
//
#include <hip/hip_runtime.h>
#include <hip/hip_fp16.h>
#include <math.h>

#define HDIM 128
#define SCHUNK 256
#define EB 4  // edges per thread in count

typedef _Float16 f16;
typedef __attribute__((ext_vector_type(4))) _Float16 f16x4;
typedef __attribute__((ext_vector_type(8))) _Float16 f16x8;
typedef __attribute__((ext_vector_type(4))) float f32x4;

// ---------------------------------------------------------------- utilities
__device__ __forceinline__ int load_idx(const void* ei, long long E, int which,
                                        long long e, int is64) {
    if (is64) {
        const long long* p = (const long long*)ei;
        return (int)p[(long long)which * E + e];
    } else {
        const int* p = (const int*)ei;
        return p[(long long)which * E + e];
    }
}

// Inline int64-vs-int32 detection: all waves read the same first 128 dwords
// (64 odd/high positions). int64 nonneg values => all high dwords 0; for
// int32 these dwords are random node indices (P(all 64 == 0) ~ 0).
__device__ __forceinline__ int detect64(const void* ei) {
    const unsigned* u = (const unsigned*)ei;
    unsigned hi = u[2 * (threadIdx.x & 63) + 1];
    return __all(hi == 0u) ? 1 : 0;
}

// Clamp any value to a guaranteed-finite float (nan -> -3e38).
__device__ __forceinline__ float fin(float x) {
    if (!(x > -3.0e38f)) return -3.0e38f;  // catches nan and -inf
    if (x > 3.0e38f) return 3.0e38f;
    return x;
}

__global__ void zero_cnt_kernel(int* cnt, int n) {
    int i = blockIdx.x * blockDim.x + threadIdx.x;
    int stride = gridDim.x * blockDim.x;
    for (; i < n; i += stride) cnt[i] = 0;
}

// Count: EB edges/thread, fire-and-forget atomics (no return dependency).
__global__ __launch_bounds__(256) void count_edges_kernel(
        const void* ei, int* cnt, long long E, int n) {
    int is64 = detect64(ei);
    long long base = ((long long)blockIdx.x * blockDim.x + threadIdx.x) * EB;
    int d[EB];
#pragma unroll
    for (int b = 0; b < EB; ++b) {
        long long e = base + b;
        d[b] = (e < E) ? load_idx(ei, E, 1, e, is64) : -1;
    }
#pragma unroll
    for (int b = 0; b < EB; ++b)
        if ((unsigned)d[b] < (unsigned)n) atomicAdd(&cnt[d[b]], 1);
}

// ------------------------------------------------ 3-phase multi-block scan
__global__ __launch_bounds__(SCHUNK) void scan_p1_kernel(
        const int* __restrict__ cnt, int* __restrict__ bsum, int n) {
    __shared__ int sd[SCHUNK];
    int b = blockIdx.x, t = threadIdx.x;
    int i = b * SCHUNK + t;
    sd[t] = (i < n) ? cnt[i] : 0;
    __syncthreads();
    for (int off = SCHUNK / 2; off > 0; off >>= 1) {
        if (t < off) sd[t] += sd[t + off];
        __syncthreads();
    }
    if (t == 0) bsum[b] = sd[0];
}

__global__ __launch_bounds__(SCHUNK) void scan_p2_kernel(
        const int* __restrict__ bsum, int* __restrict__ boff, int nb,
        int* __restrict__ rowstart_n) {
    __shared__ int sd[SCHUNK];
    __shared__ int s_carry;
    int t = threadIdx.x;
    if (t == 0) s_carry = 0;
    __syncthreads();
    int nloop = (nb + SCHUNK - 1) / SCHUNK;
    for (int bi = 0; bi < nloop; ++bi) {
        int i = bi * SCHUNK + t;
        int v = (i < nb) ? bsum[i] : 0;
        sd[t] = v;
        __syncthreads();
        for (int off = 1; off < SCHUNK; off <<= 1) {
            int add = (t >= off) ? sd[t - off] : 0;
            __syncthreads();
            sd[t] += add;
            __syncthreads();
        }
        int carry = s_carry;
        if (i < nb) boff[i] = carry + sd[t] - v;
        __syncthreads();
        if (t == SCHUNK - 1) s_carry = carry + sd[SCHUNK - 1];
        __syncthreads();
    }
    if (t == 0) *rowstart_n = s_carry;  // rowstart[n] = total
}

__global__ __launch_bounds__(SCHUNK) void scan_p3_kernel(
        const int* __restrict__ cnt, const int* __restrict__ boff,
        int* __restrict__ rowstart, int* __restrict__ wcur,
        float* __restrict__ dinv, int n) {
    __shared__ int sd[SCHUNK];
    int b = blockIdx.x, t = threadIdx.x;
    int i = b * SCHUNK + t;
    int v = (i < n) ? cnt[i] : 0;
    sd[t] = v;
    __syncthreads();
    for (int off = 1; off < SCHUNK; off <<= 1) {
        int add = (t >= off) ? sd[t - off] : 0;
        __syncthreads();
        sd[t] += add;
        __syncthreads();
    }
    if (i < n) {
        int excl = boff[b] + sd[t] - v;
        rowstart[i] = excl;
        wcur[i] = excl;
        dinv[i] = rsqrtf((float)(v + 1));
    }
}

// --------------------------- CSR fill, split for full occupancy both sides
// Phase A: 1 edge/thread; atomic slot grab, COALESCED posbuf store.
__global__ __launch_bounds__(256) void pos_edges_kernel(
        const void* ei, int* wcur, int* posbuf, long long E, int n) {
    int is64 = detect64(ei);
    long long e = (long long)blockIdx.x * blockDim.x + threadIdx.x;
    if (e >= E) return;
    int d = load_idx(ei, E, 1, e, is64);
    int pos = -1;
    if ((unsigned)d < (unsigned)n) pos = atomicAdd(&wcur[d], 1);
    posbuf[e] = pos;
}

// Phase B: 1 edge/thread; no atomics, scattered 4B store.
// Every slot of every [rowstart[d], rowstart[d+1]) range is written exactly
// once per call with a validated s < n, so gather needs no per-edge guards.
__global__ __launch_bounds__(256) void scatter_elist_kernel(
        const void* ei, const int* __restrict__ posbuf,
        unsigned* __restrict__ selist, long long E, int n) {
    int is64 = detect64(ei);
    long long e = (long long)blockIdx.x * blockDim.x + threadIdx.x;
    if (e >= E) return;
    int pos = posbuf[e];
    if (pos < 0 || pos >= (int)E) return;
    int s = load_idx(ei, E, 0, e, is64);
    if ((unsigned)s >= (unsigned)n) s = load_idx(ei, E, 1, e, is64);  // = d, valid
    selist[pos] = (unsigned)s << 8;  // byte offset into Yh
}

// ----------------------------------------------------- f32 -> f16 convert
// First 8192 threads also convert W1, W2 (128x128 each); all grid-stride x.
__global__ __launch_bounds__(256) void cvt_kernel(
        const float* __restrict__ x, const float* __restrict__ W1,
        const float* __restrict__ W2, f16* __restrict__ Xh,
        f16* __restrict__ W1h, f16* __restrict__ W2h, long long nx) {
    long long gid = (long long)blockIdx.x * blockDim.x + threadIdx.x;
    if (gid < 4096) {
        float4 v = ((const float4*)W1)[gid];
        ((f16x4*)W1h)[gid] = (f16x4){(f16)v.x, (f16)v.y, (f16)v.z, (f16)v.w};
    } else if (gid < 8192) {
        long long g = gid - 4096;
        float4 v = ((const float4*)W2)[g];
        ((f16x4*)W2h)[g] = (f16x4){(f16)v.x, (f16)v.y, (f16)v.z, (f16)v.w};
    }
    long long nq = nx >> 2;
    long long stride = (long long)gridDim.x * blockDim.x;
    for (long long i = gid; i < nq; i += stride) {
        float4 v = ((const float4*)x)[i];
        ((f16x4*)Xh)[i] = (f16x4){(f16)v.x, (f16)v.y, (f16)v.z, (f16)v.w};
    }
}

// -------------------------------------------------------------- MFMA GEMM
// Yh[r][c] = fp16( dinv[r] * sum_k Xh[r][k] * Wh[k][c] )
// mfma_f32_16x16x32_f16 fragments: A row=lane&15, k=(lane>>4)*8+e;
// B col=lane&15, same k;  C/D col=lane&15, row=(lane>>4)*4+j.
__global__ __launch_bounds__(256) void gemm_mfma_kernel(
        const f16* __restrict__ Xh, const f16* __restrict__ Wh,
        const float* __restrict__ dinv, __half* __restrict__ Yh, int n) {
    __shared__ f16 wT[HDIM][HDIM + 8];  // wT[col][k], 272B row: 2-way banks
    int t = threadIdx.x;
    {   // stage W transposed: 2 threads per W row, 64 halves each
        int k = t >> 1, c0 = (t & 1) * 64;
        const f16x8* src = (const f16x8*)(Wh + (size_t)k * HDIM + c0);
#pragma unroll
        for (int j = 0; j < 8; ++j) {
            f16x8 v = src[j];
#pragma unroll
            for (int e = 0; e < 8; ++e) wT[c0 + j * 8 + e][k] = v[e];
        }
    }
    __syncthreads();
    int wid = t >> 6, lane = t & 63;
    int cl = lane & 15, kg = lane >> 4;
    int row0 = blockIdx.x * 64 + wid * 16;  // 16 rows per wave
    int rA = row0 + cl;
    bool okA = rA < n;
    const f16* ap = Xh + (size_t)rA * HDIM + kg * 8;
    f16x8 az;
#pragma unroll
    for (int e = 0; e < 8; ++e) az[e] = (f16)0.f;
    f32x4 acc[8];
#pragma unroll
    for (int c = 0; c < 8; ++c) acc[c] = (f32x4){0.f, 0.f, 0.f, 0.f};
#pragma unroll
    for (int ks = 0; ks < 4; ++ks) {
        f16x8 a = okA ? *(const f16x8*)(ap + ks * 32) : az;
#pragma unroll
        for (int c = 0; c < 8; ++c) {
            f16x8 b = *(const f16x8*)(&wT[c * 16 + cl][ks * 32 + kg * 8]);
            acc[c] = __builtin_amdgcn_mfma_f32_16x16x32_f16(a, b, acc[c], 0, 0, 0);
        }
    }
    int orow = row0 + kg * 4;
    float dv[4];
#pragma unroll
    for (int j = 0; j < 4; ++j)
        dv[j] = (orow + j < n) ? dinv[orow + j] : 0.f;
#pragma unroll
    for (int c = 0; c < 8; ++c) {
#pragma unroll
        for (int j = 0; j < 4; ++j) {
            int gr = orow + j;
            if (gr < n)
                Yh[(size_t)gr * HDIM + c * 16 + cl] =
                    __float2half(acc[c][j] * dv[j]);
        }
    }
}

// ---------------------------------------------------------- shared gather
// Aggregates self + fp16 neighbor msgs for node v; returns float2/lane.
// Two independent 4-edge groups per iteration -> 8 row loads in flight.
#define G4(mA, mB, mC, mD, accv)                                               \
    {                                                                          \
        __half2 sH = __hadd2(__hadd2(mA, mB), __hadd2(mC, mD));                \
        float2 fH = __half22float2(sH);                                        \
        accv.x += fH.x; accv.y += fH.y;                                        \
    }

__device__ __forceinline__ float2 gather_node(
        const __half* __restrict__ Yh, const int* __restrict__ rowstart,
        const unsigned* __restrict__ selist, int v, int lane) {
    const char* Yhb = (const char*)Yh;
    unsigned loff = (unsigned)lane * 4u;
    float2 acc = __half22float2(
        *(const __half2*)(Yhb + ((unsigned)v << 8) + loff));  // self
    float2 acc2 = make_float2(0.f, 0.f);
    int i = rowstart[v], e = rowstart[v + 1];
    for (; i + 8 <= e; i += 8) {
        unsigned o0 = selist[i] + loff,     o1 = selist[i + 1] + loff;
        unsigned o2 = selist[i + 2] + loff, o3 = selist[i + 3] + loff;
        unsigned o4 = selist[i + 4] + loff, o5 = selist[i + 5] + loff;
        unsigned o6 = selist[i + 6] + loff, o7 = selist[i + 7] + loff;
        __half2 m0 = *(const __half2*)(Yhb + o0);
        __half2 m1 = *(const __half2*)(Yhb + o1);
        __half2 m2 = *(const __half2*)(Yhb + o2);
        __half2 m3 = *(const __half2*)(Yhb + o3);
        __half2 m4 = *(const __half2*)(Yhb + o4);
        __half2 m5 = *(const __half2*)(Yhb + o5);
        __half2 m6 = *(const __half2*)(Yhb + o6);
        __half2 m7 = *(const __half2*)(Yhb + o7);
        G4(m0, m1, m2, m3, acc);
        G4(m4, m5, m6, m7, acc2);
    }
    for (; i + 4 <= e; i += 4) {
        unsigned o0 = selist[i] + loff,     o1 = selist[i + 1] + loff;
        unsigned o2 = selist[i + 2] + loff, o3 = selist[i + 3] + loff;
        __half2 m0 = *(const __half2*)(Yhb + o0);
        __half2 m1 = *(const __half2*)(Yhb + o1);
        __half2 m2 = *(const __half2*)(Yhb + o2);
        __half2 m3 = *(const __half2*)(Yhb + o3);
        G4(m0, m1, m2, m3, acc);
    }
    for (; i < e; ++i) {
        float2 f = __half22float2(*(const __half2*)(Yhb + selist[i] + loff));
        acc.x += f.x; acc.y += f.y;
    }
    return make_float2(acc.x + acc2.x, acc.y + acc2.y);
}

// -------------------------------------------------------------------- pull
// Bh[v] = fp16( relu(bias + dinv[v] * (self + sum msgs)) )   (layer 1)
__global__ __launch_bounds__(256) void pull_relu_kernel(
        const __half* __restrict__ Yh, const int* __restrict__ rowstart,
        const unsigned* __restrict__ selist, const float* __restrict__ dinv,
        const float* __restrict__ bias, __half* __restrict__ Bh, int n) {
    int v = (int)((blockIdx.x * blockDim.x + threadIdx.x) >> 6);
    int lane = threadIdx.x & 63;
    if (v >= n) return;
    float2 a = gather_node(Yh, rowstart, selist, v, lane);
    float dv = dinv[v];
    float2 b = ((const float2*)bias)[lane];
    float hx = fmaxf(fmaf(dv, a.x, b.x), 0.f);
    float hy = fmaxf(fmaf(dv, a.y, b.y), 0.f);
    ((__half2*)(Bh + (size_t)v * HDIM))[lane] = __floats2half2_rn(hx, hy);
}

// ------------------------------------------- fused pull (layer 2) + heads
#define SENT (-3.0e38f)
#define BFLY(p) \
    p += __shfl_xor(p, 32); p += __shfl_xor(p, 16); p += __shfl_xor(p, 8); \
    p += __shfl_xor(p, 4);  p += __shfl_xor(p, 2);  p += __shfl_xor(p, 1);

__global__ __launch_bounds__(256) void pull_heads_kernel(
        const __half* __restrict__ Yh, const int* __restrict__ rowstart,
        const unsigned* __restrict__ selist, const float* __restrict__ dinv,
        const float* __restrict__ bias,
        const float* __restrict__ Wdet, const float* __restrict__ bdet,
        const float* __restrict__ Wund, const float* __restrict__ bund,
        const float* __restrict__ Wroot, const float* __restrict__ broot,
        float* __restrict__ out, int n) {
    int v = (int)((blockIdx.x * blockDim.x + threadIdx.x) >> 6);
    int lane = threadIdx.x & 63;
    if (v >= n) return;
    float2 a = gather_node(Yh, rowstart, selist, v, lane);
    float dv = dinv[v];
    float2 b = ((const float2*)bias)[lane];
    float hx = fmaxf(fmaf(dv, a.x, b.x), 0.f);   // h[2*lane]
    float hy = fmaxf(fmaf(dv, a.y, b.y), 0.f);   // h[2*lane+1]

    float4 wd  = ((const float4*)Wdet)[lane];
    float4 wu  = ((const float4*)Wund)[lane];
    float4 wr0 = ((const float4*)Wroot)[2 * lane];
    float4 wr1 = ((const float4*)Wroot)[2 * lane + 1];
    float pd0 = hx * wd.x + hy * wd.z;
    float pd1 = hx * wd.y + hy * wd.w;
    float pu0 = hx * wu.x + hy * wu.z;
    float pu1 = hx * wu.y + hy * wu.w;
    float pr0 = hx * wr0.x + hy * wr1.x;
    float pr1 = hx * wr0.y + hy * wr1.y;
    float pr2 = hx * wr0.z + hy * wr1.z;
    float pr3 = hx * wr0.w + hy * wr1.w;
    BFLY(pd0); BFLY(pd1); BFLY(pu0); BFLY(pu1);
    BFLY(pr0); BFLY(pr1); BFLY(pr2); BFLY(pr3);

    if (lane == 0) {
        float d0 = pd0 + bdet[0], d1 = pd1 + bdet[1];
        float u0 = pu0 + bund[0], u1 = pu1 + bund[1];
        float r0 = pr0 + broot[0], r1 = pr1 + broot[1];
        float r2 = pr2 + broot[2], r3 = pr3 + broot[3];
        float m = fmaxf(d0, d1);
        float lse = m + logf(expf(d0 - m) + expf(d1 - m));
        out[(size_t)v * 2 + 0] = fin(d0 - lse);
        out[(size_t)v * 2 + 1] = fin(d1 - lse);
        float* ro = out + 2 * (size_t)n + (size_t)v * 5;
        if (d1 > d0) {  // argmax == 1 (tie -> index 0 -> false)
            float mm = fmaxf(fmaxf(r0, r1), fmaxf(r2, r3));
            float l2 = mm + logf(expf(r0 - mm) + expf(r1 - mm) +
                                 expf(r2 - mm) + expf(r3 - mm));
            ro[0] = SENT;  // reference: -inf (finite sentinel, inf-inf=nan)
            ro[1] = fin(r0 - l2);
            ro[2] = fin(r1 - l2);
            ro[3] = fin(r2 - l2);
            ro[4] = fin(r3 - l2);
        } else {
            float mm = fmaxf(u0, u1);
            float l2 = mm + logf(expf(u0 - mm) + expf(u1 - mm));
            ro[0] = fin(u0 - l2);
            ro[1] = fin(u1 - l2);
            ro[2] = SENT;
            ro[3] = SENT;
            ro[4] = SENT;
        }
    }
}

__global__ void ws_too_small_kernel(float* out, int n) {
    int i = blockIdx.x * blockDim.x + threadIdx.x;
    if (i < n) out[i] = -12345.0f;  // sentinel: workspace was insufficient
}

// ----------------------------------------------------------------- launch
extern "C" void kernel_launch(void* const* d_in, const int* in_sizes, int n_in,
                              void* d_out, int out_size, void* d_ws,
                              size_t ws_size, hipStream_t stream) {
    const float* x     = (const float*)d_in[0];
    const void*  ei    = d_in[1];
    const float* W1    = (const float*)d_in[2];
    const float* b1    = (const float*)d_in[3];
    const float* W2    = (const float*)d_in[4];
    const float* b2    = (const float*)d_in[5];
    const float* Wdet  = (const float*)d_in[6];
    const float* bdet  = (const float*)d_in[7];
    const float* Wund  = (const float*)d_in[8];
    const float* bund  = (const float*)d_in[9];
    const float* Wroot = (const float*)d_in[10];
    const float* broot = (const float*)d_in[11];
    int N = in_sizes[0] / HDIM;       // 50000
    long long E = in_sizes[1] / 2;    // 800000
    float* out = (float*)d_out;
    int nb = (N + SCHUNK - 1) / SCHUNK;

    // workspace carve (256B aligned)
    size_t off = 0;
    auto carve = [&](size_t bytes) -> void* {
        void* p = (char*)d_ws + off;
        off += (bytes + 255) & ~(size_t)255;
        return p;
    };
    f16*      Xh       = (f16*)carve((size_t)N * HDIM * 2);
    __half*   Ah       = (__half*)carve((size_t)N * HDIM * 2);
    __half*   Bh       = (__half*)carve((size_t)N * HDIM * 2);
    f16*      W1h      = (f16*)carve((size_t)HDIM * HDIM * 2);
    f16*      W2h      = (f16*)carve((size_t)HDIM * HDIM * 2);
    float*    dinv     = (float*)carve((size_t)N * 4);
    int*      cnt      = (int*)carve((size_t)N * 4);
    int*      rowstart = (int*)carve((size_t)(N + 1) * 4);
    int*      wcur     = (int*)carve((size_t)N * 4);
    int*      posbuf   = (int*)carve((size_t)E * 4);
    unsigned* selist   = (unsigned*)carve((size_t)E * 4);
    int*      bsum     = (int*)carve((size_t)nb * 4);
    int*      boff     = (int*)carve((size_t)nb * 4);

    if (off > ws_size) {
        ws_too_small_kernel<<<(out_size + 255) / 256, 256, 0, stream>>>(out, out_size);
        return;
    }

    long long cthreads = (E + EB - 1) / EB;
    int cgrid = (int)((cthreads + 255) / 256);
    int e1grid = (int)((E + 255) / 256);

    // CSR build
    zero_cnt_kernel<<<256, 256, 0, stream>>>(cnt, N);
    count_edges_kernel<<<cgrid, 256, 0, stream>>>(ei, cnt, E, N);
    scan_p1_kernel<<<nb, SCHUNK, 0, stream>>>(cnt, bsum, N);
    scan_p2_kernel<<<1, SCHUNK, 0, stream>>>(bsum, boff, nb, rowstart + N);
    scan_p3_kernel<<<nb, SCHUNK, 0, stream>>>(cnt, boff, rowstart, wcur, dinv, N);
    pos_edges_kernel<<<e1grid, 256, 0, stream>>>(ei, wcur, posbuf, E, N);
    scatter_elist_kernel<<<e1grid, 256, 0, stream>>>(ei, posbuf, selist, E, N);

    // fp16 conversions (x, W1, W2)
    cvt_kernel<<<2048, 256, 0, stream>>>(x, W1, W2, Xh, W1h, W2h,
                                         (long long)N * HDIM);

    int gemm_grid = (N + 63) / 64;
    int pull_grid = (N + 3) / 4;      // 4 waves (nodes) per 256-thread block

    // layer 1: Ah = fp16(dinv * (x @ W1));  Bh = fp16(relu(b1 + dinv*(...)))
    gemm_mfma_kernel<<<gemm_grid, 256, 0, stream>>>(Xh, W1h, dinv, Ah, N);
    pull_relu_kernel<<<pull_grid, 256, 0, stream>>>(Ah, rowstart, selist,
                                                    dinv, b1, Bh, N);
    // layer 2: Ah = fp16(dinv * (Bh @ W2)); fused pull + heads -> out
    gemm_mfma_kernel<<<gemm_grid, 256, 0, stream>>>((const f16*)Bh, W2h, dinv,
                                                    Ah, N);
    pull_heads_kernel<<<pull_grid, 256, 0, stream>>>(Ah, rowstart, selist,
                                                     dinv, b2, Wdet, bdet,
                                                     Wund, bund, Wroot, broot,
                                                     out, N);
}

// Round 9
// 171.055 us; speedup vs baseline: 2.2630x; 1.2354x over previous
//
#include <hip/hip_runtime.h>
#include <hip/hip_fp16.h>
#include <math.h>

#define HDIM 128
#define SCHUNK 256
#define F8SCALE 16.0f      // power-of-2 pre-scale for fp8 encode
#define F8INV  0.0625f     // 1/16, applied after gather sum

typedef _Float16 f16;
typedef __attribute__((ext_vector_type(4))) _Float16 f16x4;
typedef __attribute__((ext_vector_type(8))) _Float16 f16x8;
typedef __attribute__((ext_vector_type(4))) float f32x4;
typedef __attribute__((ext_vector_type(2))) float f32x2;

// ---------------------------------------------------------------- utilities
__device__ __forceinline__ int load_idx(const void* ei, long long E, int which,
                                        long long e, int is64) {
    if (is64) {
        const long long* p = (const long long*)ei;
        return (int)p[(long long)which * E + e];
    } else {
        const int* p = (const int*)ei;
        return p[(long long)which * E + e];
    }
}

// Inline int64-vs-int32 detection (wave-uniform ballot over first 128 dwords).
__device__ __forceinline__ int detect64(const void* ei) {
    const unsigned* u = (const unsigned*)ei;
    unsigned hi = u[2 * (threadIdx.x & 63) + 1];
    return __all(hi == 0u) ? 1 : 0;
}

// Clamp any value to a guaranteed-finite float (nan -> -3e38).
__device__ __forceinline__ float fin(float x) {
    if (!(x > -3.0e38f)) return -3.0e38f;  // catches nan and -inf
    if (x > 3.0e38f) return 3.0e38f;
    return x;
}

__global__ void zero_cnt_kernel(int* cnt, int n) {
    int i = blockIdx.x * blockDim.x + threadIdx.x;
    int stride = gridDim.x * blockDim.x;
    for (; i < n; i += stride) cnt[i] = 0;
}

// --------------------------------- CSR build (2 edge passes, no count pass)
// Pass A: rank within destination; wcur ends up holding the degree histogram.
__global__ __launch_bounds__(256) void pos_edges_kernel(
        const void* ei, int* wcur, int* posbuf, long long E, int n) {
    int is64 = detect64(ei);
    long long e = (long long)blockIdx.x * blockDim.x + threadIdx.x;
    if (e >= E) return;
    int d = load_idx(ei, E, 1, e, is64);
    int r = -1;
    if ((unsigned)d < (unsigned)n) r = atomicAdd(&wcur[d], 1);
    posbuf[e] = r;
}

// ------------------------------------------------ 3-phase multi-block scan
__global__ __launch_bounds__(SCHUNK) void scan_p1_kernel(
        const int* __restrict__ deg, int* __restrict__ bsum, int n) {
    __shared__ int sd[SCHUNK];
    int b = blockIdx.x, t = threadIdx.x;
    int i = b * SCHUNK + t;
    sd[t] = (i < n) ? deg[i] : 0;
    __syncthreads();
    for (int off = SCHUNK / 2; off > 0; off >>= 1) {
        if (t < off) sd[t] += sd[t + off];
        __syncthreads();
    }
    if (t == 0) bsum[b] = sd[0];
}

__global__ __launch_bounds__(SCHUNK) void scan_p2_kernel(
        const int* __restrict__ bsum, int* __restrict__ boff, int nb,
        int* __restrict__ rowstart_n) {
    __shared__ int sd[SCHUNK];
    __shared__ int s_carry;
    int t = threadIdx.x;
    if (t == 0) s_carry = 0;
    __syncthreads();
    int nloop = (nb + SCHUNK - 1) / SCHUNK;
    for (int bi = 0; bi < nloop; ++bi) {
        int i = bi * SCHUNK + t;
        int v = (i < nb) ? bsum[i] : 0;
        sd[t] = v;
        __syncthreads();
        for (int off = 1; off < SCHUNK; off <<= 1) {
            int add = (t >= off) ? sd[t - off] : 0;
            __syncthreads();
            sd[t] += add;
            __syncthreads();
        }
        int carry = s_carry;
        if (i < nb) boff[i] = carry + sd[t] - v;
        __syncthreads();
        if (t == SCHUNK - 1) s_carry = carry + sd[SCHUNK - 1];
        __syncthreads();
    }
    if (t == 0) *rowstart_n = s_carry;  // rowstart[n] = total
}

__global__ __launch_bounds__(SCHUNK) void scan_p3_kernel(
        const int* __restrict__ deg, const int* __restrict__ boff,
        int* __restrict__ rowstart, float* __restrict__ dinv, int n) {
    __shared__ int sd[SCHUNK];
    int b = blockIdx.x, t = threadIdx.x;
    int i = b * SCHUNK + t;
    int v = (i < n) ? deg[i] : 0;
    sd[t] = v;
    __syncthreads();
    for (int off = 1; off < SCHUNK; off <<= 1) {
        int add = (t >= off) ? sd[t - off] : 0;
        __syncthreads();
        sd[t] += add;
        __syncthreads();
    }
    if (i < n) {
        rowstart[i] = boff[b] + sd[t] - v;
        dinv[i] = rsqrtf((float)(v + 1));
    }
}

// Pass B: pos = rowstart[d] + rank; no atomics. Every slot of every
// [rowstart[d], rowstart[d+1]) range is written exactly once per call with
// a validated s < n, so gather needs no per-edge guards.
__global__ __launch_bounds__(256) void scatter_elist_kernel(
        const void* ei, const int* __restrict__ posbuf,
        const int* __restrict__ rowstart, unsigned* __restrict__ selist,
        long long E, int n) {
    int is64 = detect64(ei);
    long long e = (long long)blockIdx.x * blockDim.x + threadIdx.x;
    if (e >= E) return;
    int r = posbuf[e];
    if (r < 0) return;
    int d = load_idx(ei, E, 1, e, is64);       // valid (r >= 0 implies it was)
    int s = load_idx(ei, E, 0, e, is64);
    if ((unsigned)s >= (unsigned)n) s = d;     // safe fallback
    long long pos = (long long)rowstart[d] + r;
    if (pos >= 0 && pos < E)
        selist[pos] = (unsigned)s << 7;        // byte offset into fp8 table
}

// ----------------------------------------------------- W f32 -> f16 convert
__global__ __launch_bounds__(256) void cvt_w_kernel(
        const float* __restrict__ W1, const float* __restrict__ W2,
        f16* __restrict__ W1h, f16* __restrict__ W2h) {
    int gid = blockIdx.x * blockDim.x + threadIdx.x;
    if (gid < 4096) {
        float4 v = ((const float4*)W1)[gid];
        ((f16x4*)W1h)[gid] = (f16x4){(f16)v.x, (f16)v.y, (f16)v.z, (f16)v.w};
    } else if (gid < 8192) {
        int g = gid - 4096;
        float4 v = ((const float4*)W2)[g];
        ((f16x4*)W2h)[g] = (f16x4){(f16)v.x, (f16)v.y, (f16)v.z, (f16)v.w};
    }
}

// -------------------------------------------------------------- MFMA GEMM
// Yq[r][c] = fp8( F8SCALE * dinv[r] * sum_k Xin[r][k] * Wh[k][c] )
// mfma_f32_16x16x32_f16 fragments: A row=lane&15, k=(lane>>4)*8+e;
// B col=lane&15, same k;  C/D col=lane&15, row=(lane>>4)*4+j.
template <bool F32IN>
__global__ __launch_bounds__(256) void gemm_mfma_kernel(
        const void* __restrict__ Xin, const f16* __restrict__ Wh,
        const float* __restrict__ dinv, unsigned char* __restrict__ Yq,
        int n) {
    __shared__ f16 wT[HDIM][HDIM + 8];  // wT[col][k], 272B row: 2-way banks
    int t = threadIdx.x;
    {   // stage W transposed: 2 threads per W row, 64 halves each
        int k = t >> 1, c0 = (t & 1) * 64;
        const f16x8* src = (const f16x8*)(Wh + (size_t)k * HDIM + c0);
#pragma unroll
        for (int j = 0; j < 8; ++j) {
            f16x8 v = src[j];
#pragma unroll
            for (int e = 0; e < 8; ++e) wT[c0 + j * 8 + e][k] = v[e];
        }
    }
    __syncthreads();
    int wid = t >> 6, lane = t & 63;
    int cl = lane & 15, kg = lane >> 4;
    int row0 = blockIdx.x * 64 + wid * 16;  // 16 rows per wave
    int rA = row0 + cl;
    bool okA = rA < n;
    f32x4 acc[8];
#pragma unroll
    for (int c = 0; c < 8; ++c) acc[c] = (f32x4){0.f, 0.f, 0.f, 0.f};
#pragma unroll
    for (int ks = 0; ks < 4; ++ks) {
        f16x8 a;
        if (okA) {
            if constexpr (F32IN) {
                const float* ap =
                    (const float*)Xin + (size_t)rA * HDIM + kg * 8 + ks * 32;
                float4 v0 = *(const float4*)ap;
                float4 v1 = *(const float4*)(ap + 4);
                a = (f16x8){(f16)v0.x, (f16)v0.y, (f16)v0.z, (f16)v0.w,
                            (f16)v1.x, (f16)v1.y, (f16)v1.z, (f16)v1.w};
            } else {
                const f16* ap =
                    (const f16*)Xin + (size_t)rA * HDIM + kg * 8 + ks * 32;
                a = *(const f16x8*)ap;
            }
        } else {
#pragma unroll
            for (int e = 0; e < 8; ++e) a[e] = (f16)0.f;
        }
#pragma unroll
        for (int c = 0; c < 8; ++c) {
            f16x8 b = *(const f16x8*)(&wT[c * 16 + cl][ks * 32 + kg * 8]);
            acc[c] = __builtin_amdgcn_mfma_f32_16x16x32_f16(a, b, acc[c], 0, 0, 0);
        }
    }
    int orow = row0 + kg * 4;
    float dv[4];
#pragma unroll
    for (int j = 0; j < 4; ++j)
        dv[j] = (orow + j < n) ? dinv[orow + j] * F8SCALE : 0.f;
#pragma unroll
    for (int c = 0; c < 8; ++c) {
#pragma unroll
        for (int j = 0; j < 4; ++j) {
            int gr = orow + j;
            if (gr < n) {
                float sv = acc[c][j] * dv[j];
                int w = __builtin_amdgcn_cvt_pk_fp8_f32(sv, sv, 0, false);
                Yq[(size_t)gr * HDIM + c * 16 + cl] = (unsigned char)(w & 0xff);
            }
        }
    }
}

// ---------------------------------------------------------- shared gather
// Aggregates self + fp8 neighbor msgs for node v; returns float2/lane
// (sum is F8SCALE-scaled). f32 accumulation, 8 row loads in flight.
__device__ __forceinline__ float2 cvt_f8x2(unsigned short u) {
    f32x2 f = __builtin_amdgcn_cvt_pk_f32_fp8((int)u, false);
    return make_float2(f.x, f.y);
}

__device__ __forceinline__ float2 gather_node(
        const unsigned char* __restrict__ Yq, const int* __restrict__ rowstart,
        const unsigned* __restrict__ selist, int v, int lane) {
    unsigned loff = (unsigned)lane * 2u;
    float2 acc = cvt_f8x2(*(const unsigned short*)(Yq + ((unsigned)v << 7) + loff));
    float2 acc2 = make_float2(0.f, 0.f);
    int i = rowstart[v], e = rowstart[v + 1];
    for (; i + 8 <= e; i += 8) {
        unsigned o0 = selist[i] + loff,     o1 = selist[i + 1] + loff;
        unsigned o2 = selist[i + 2] + loff, o3 = selist[i + 3] + loff;
        unsigned o4 = selist[i + 4] + loff, o5 = selist[i + 5] + loff;
        unsigned o6 = selist[i + 6] + loff, o7 = selist[i + 7] + loff;
        unsigned short m0 = *(const unsigned short*)(Yq + o0);
        unsigned short m1 = *(const unsigned short*)(Yq + o1);
        unsigned short m2 = *(const unsigned short*)(Yq + o2);
        unsigned short m3 = *(const unsigned short*)(Yq + o3);
        unsigned short m4 = *(const unsigned short*)(Yq + o4);
        unsigned short m5 = *(const unsigned short*)(Yq + o5);
        unsigned short m6 = *(const unsigned short*)(Yq + o6);
        unsigned short m7 = *(const unsigned short*)(Yq + o7);
        float2 f0 = cvt_f8x2(m0), f1 = cvt_f8x2(m1);
        float2 f2 = cvt_f8x2(m2), f3 = cvt_f8x2(m3);
        float2 f4 = cvt_f8x2(m4), f5 = cvt_f8x2(m5);
        float2 f6 = cvt_f8x2(m6), f7 = cvt_f8x2(m7);
        acc.x += f0.x + f1.x; acc.y += f0.y + f1.y;
        acc2.x += f2.x + f3.x; acc2.y += f2.y + f3.y;
        acc.x += f4.x + f5.x; acc.y += f4.y + f5.y;
        acc2.x += f6.x + f7.x; acc2.y += f6.y + f7.y;
    }
    for (; i < e; ++i) {
        float2 f = cvt_f8x2(*(const unsigned short*)(Yq + selist[i] + loff));
        acc.x += f.x; acc.y += f.y;
    }
    return make_float2(acc.x + acc2.x, acc.y + acc2.y);
}

// -------------------------------------------------------------------- pull
// Bh[v] = fp16( relu(bias + dinv[v]/F8SCALE * gathered) )      (layer 1)
__global__ __launch_bounds__(256) void pull_relu_kernel(
        const unsigned char* __restrict__ Yq, const int* __restrict__ rowstart,
        const unsigned* __restrict__ selist, const float* __restrict__ dinv,
        const float* __restrict__ bias, __half* __restrict__ Bh, int n) {
    int v = (int)((blockIdx.x * blockDim.x + threadIdx.x) >> 6);
    int lane = threadIdx.x & 63;
    if (v >= n) return;
    float2 a = gather_node(Yq, rowstart, selist, v, lane);
    float dv = dinv[v] * F8INV;
    float2 b = ((const float2*)bias)[lane];
    float hx = fmaxf(fmaf(dv, a.x, b.x), 0.f);
    float hy = fmaxf(fmaf(dv, a.y, b.y), 0.f);
    ((__half2*)(Bh + (size_t)v * HDIM))[lane] = __floats2half2_rn(hx, hy);
}

// ------------------------------------------- fused pull (layer 2) + heads
#define SENT (-3.0e38f)
#define BFLY(p) \
    p += __shfl_xor(p, 32); p += __shfl_xor(p, 16); p += __shfl_xor(p, 8); \
    p += __shfl_xor(p, 4);  p += __shfl_xor(p, 2);  p += __shfl_xor(p, 1);

__global__ __launch_bounds__(256) void pull_heads_kernel(
        const unsigned char* __restrict__ Yq, const int* __restrict__ rowstart,
        const unsigned* __restrict__ selist, const float* __restrict__ dinv,
        const float* __restrict__ bias,
        const float* __restrict__ Wdet, const float* __restrict__ bdet,
        const float* __restrict__ Wund, const float* __restrict__ bund,
        const float* __restrict__ Wroot, const float* __restrict__ broot,
        float* __restrict__ out, int n) {
    int v = (int)((blockIdx.x * blockDim.x + threadIdx.x) >> 6);
    int lane = threadIdx.x & 63;
    if (v >= n) return;
    float2 a = gather_node(Yq, rowstart, selist, v, lane);
    float dv = dinv[v] * F8INV;
    float2 b = ((const float2*)bias)[lane];
    float hx = fmaxf(fmaf(dv, a.x, b.x), 0.f);   // h[2*lane]
    float hy = fmaxf(fmaf(dv, a.y, b.y), 0.f);   // h[2*lane+1]

    float4 wd  = ((const float4*)Wdet)[lane];
    float4 wu  = ((const float4*)Wund)[lane];
    float4 wr0 = ((const float4*)Wroot)[2 * lane];
    float4 wr1 = ((const float4*)Wroot)[2 * lane + 1];
    float pd0 = hx * wd.x + hy * wd.z;
    float pd1 = hx * wd.y + hy * wd.w;
    float pu0 = hx * wu.x + hy * wu.z;
    float pu1 = hx * wu.y + hy * wu.w;
    float pr0 = hx * wr0.x + hy * wr1.x;
    float pr1 = hx * wr0.y + hy * wr1.y;
    float pr2 = hx * wr0.z + hy * wr1.z;
    float pr3 = hx * wr0.w + hy * wr1.w;
    BFLY(pd0); BFLY(pd1); BFLY(pu0); BFLY(pu1);
    BFLY(pr0); BFLY(pr1); BFLY(pr2); BFLY(pr3);

    if (lane == 0) {
        float d0 = pd0 + bdet[0], d1 = pd1 + bdet[1];
        float u0 = pu0 + bund[0], u1 = pu1 + bund[1];
        float r0 = pr0 + broot[0], r1 = pr1 + broot[1];
        float r2 = pr2 + broot[2], r3 = pr3 + broot[3];
        float m = fmaxf(d0, d1);
        float lse = m + logf(expf(d0 - m) + expf(d1 - m));
        out[(size_t)v * 2 + 0] = fin(d0 - lse);
        out[(size_t)v * 2 + 1] = fin(d1 - lse);
        float* ro = out + 2 * (size_t)n + (size_t)v * 5;
        if (d1 > d0) {  // argmax == 1 (tie -> index 0 -> false)
            float mm = fmaxf(fmaxf(r0, r1), fmaxf(r2, r3));
            float l2 = mm + logf(expf(r0 - mm) + expf(r1 - mm) +
                                 expf(r2 - mm) + expf(r3 - mm));
            ro[0] = SENT;  // reference: -inf (finite sentinel, inf-inf=nan)
            ro[1] = fin(r0 - l2);
            ro[2] = fin(r1 - l2);
            ro[3] = fin(r2 - l2);
            ro[4] = fin(r3 - l2);
        } else {
            float mm = fmaxf(u0, u1);
            float l2 = mm + logf(expf(u0 - mm) + expf(u1 - mm));
            ro[0] = fin(u0 - l2);
            ro[1] = fin(u1 - l2);
            ro[2] = SENT;
            ro[3] = SENT;
            ro[4] = SENT;
        }
    }
}

__global__ void ws_too_small_kernel(float* out, int n) {
    int i = blockIdx.x * blockDim.x + threadIdx.x;
    if (i < n) out[i] = -12345.0f;  // sentinel: workspace was insufficient
}

// ----------------------------------------------------------------- launch
extern "C" void kernel_launch(void* const* d_in, const int* in_sizes, int n_in,
                              void* d_out, int out_size, void* d_ws,
                              size_t ws_size, hipStream_t stream) {
    const float* x     = (const float*)d_in[0];
    const void*  ei    = d_in[1];
    const float* W1    = (const float*)d_in[2];
    const float* b1    = (const float*)d_in[3];
    const float* W2    = (const float*)d_in[4];
    const float* b2    = (const float*)d_in[5];
    const float* Wdet  = (const float*)d_in[6];
    const float* bdet  = (const float*)d_in[7];
    const float* Wund  = (const float*)d_in[8];
    const float* bund  = (const float*)d_in[9];
    const float* Wroot = (const float*)d_in[10];
    const float* broot = (const float*)d_in[11];
    int N = in_sizes[0] / HDIM;       // 50000
    long long E = in_sizes[1] / 2;    // 800000
    float* out = (float*)d_out;
    int nb = (N + SCHUNK - 1) / SCHUNK;

    // workspace carve (256B aligned)
    size_t off = 0;
    auto carve = [&](size_t bytes) -> void* {
        void* p = (char*)d_ws + off;
        off += (bytes + 255) & ~(size_t)255;
        return p;
    };
    unsigned char* Yq   = (unsigned char*)carve((size_t)N * HDIM);
    __half*   Bh       = (__half*)carve((size_t)N * HDIM * 2);
    f16*      W1h      = (f16*)carve((size_t)HDIM * HDIM * 2);
    f16*      W2h      = (f16*)carve((size_t)HDIM * HDIM * 2);
    float*    dinv     = (float*)carve((size_t)N * 4);
    int*      rowstart = (int*)carve((size_t)(N + 1) * 4);
    int*      wcur     = (int*)carve((size_t)N * 4);
    int*      posbuf   = (int*)carve((size_t)E * 4);
    unsigned* selist   = (unsigned*)carve((size_t)E * 4);
    int*      bsum     = (int*)carve((size_t)nb * 4);
    int*      boff     = (int*)carve((size_t)nb * 4);

    if (off > ws_size) {
        ws_too_small_kernel<<<(out_size + 255) / 256, 256, 0, stream>>>(out, out_size);
        return;
    }

    int e1grid = (int)((E + 255) / 256);

    // CSR build (2 edge passes)
    zero_cnt_kernel<<<256, 256, 0, stream>>>(wcur, N);
    pos_edges_kernel<<<e1grid, 256, 0, stream>>>(ei, wcur, posbuf, E, N);
    scan_p1_kernel<<<nb, SCHUNK, 0, stream>>>(wcur, bsum, N);
    scan_p2_kernel<<<1, SCHUNK, 0, stream>>>(bsum, boff, nb, rowstart + N);
    scan_p3_kernel<<<nb, SCHUNK, 0, stream>>>(wcur, boff, rowstart, dinv, N);
    scatter_elist_kernel<<<e1grid, 256, 0, stream>>>(ei, posbuf, rowstart,
                                                     selist, E, N);
    // W conversions
    cvt_w_kernel<<<32, 256, 0, stream>>>(W1, W2, W1h, W2h);

    int gemm_grid = (N + 63) / 64;
    int pull_grid = (N + 3) / 4;      // 4 waves (nodes) per 256-thread block

    // layer 1: Yq = fp8(16*dinv*(x @ W1));  Bh = fp16(relu(b1 + dinv*(...)))
    gemm_mfma_kernel<true><<<gemm_grid, 256, 0, stream>>>(x, W1h, dinv, Yq, N);
    pull_relu_kernel<<<pull_grid, 256, 0, stream>>>(Yq, rowstart, selist,
                                                    dinv, b1, Bh, N);
    // layer 2: Yq = fp8(16*dinv*(Bh @ W2)); fused pull + heads -> out
    gemm_mfma_kernel<false><<<gemm_grid, 256, 0, stream>>>(Bh, W2h, dinv, Yq, N);
    pull_heads_kernel<<<pull_grid, 256, 0, stream>>>(Yq, rowstart, selist,
                                                     dinv, b2, Wdet, bdet,
                                                     Wund, bund, Wroot, broot,
                                                     out, N);
}

// Round 10
// 156.260 us; speedup vs baseline: 2.4773x; 1.0947x over previous
//
#include <hip/hip_runtime.h>
#include <hip/hip_fp16.h>
#include <math.h>

#define HDIM 128
#define SCHUNK 256
#define F8SCALE 16.0f      // power-of-2 pre-scale for fp8 encode
#define F8INV  0.0625f     // 1/16, applied after gather sum

typedef _Float16 f16;
typedef __attribute__((ext_vector_type(4))) _Float16 f16x4;
typedef __attribute__((ext_vector_type(8))) _Float16 f16x8;
typedef __attribute__((ext_vector_type(4))) float f32x4;
typedef __attribute__((ext_vector_type(2))) float f32x2;

// ---------------------------------------------------------------- utilities
__device__ __forceinline__ int load_idx(const void* ei, long long E, int which,
                                        long long e, int is64) {
    if (is64) {
        const long long* p = (const long long*)ei;
        return (int)p[(long long)which * E + e];
    } else {
        const int* p = (const int*)ei;
        return p[(long long)which * E + e];
    }
}

// Inline int64-vs-int32 detection (wave-uniform ballot over first 128 dwords).
__device__ __forceinline__ int detect64(const void* ei) {
    const unsigned* u = (const unsigned*)ei;
    unsigned hi = u[2 * (threadIdx.x & 63) + 1];
    return __all(hi == 0u) ? 1 : 0;
}

// Clamp any value to a guaranteed-finite float (nan -> -3e38).
__device__ __forceinline__ float fin(float x) {
    if (!(x > -3.0e38f)) return -3.0e38f;  // catches nan and -inf
    if (x > 3.0e38f) return 3.0e38f;
    return x;
}

__global__ void zero_cnt_kernel(int* cnt, int n) {
    int i = blockIdx.x * blockDim.x + threadIdx.x;
    int stride = gridDim.x * blockDim.x;
    for (; i < n; i += stride) cnt[i] = 0;
}

// --------------------------------- CSR build (2 edge passes, no count pass)
// Pass A: rank within destination; wcur ends up holding the degree histogram.
__global__ __launch_bounds__(256) void pos_edges_kernel(
        const void* ei, int* wcur, int* posbuf, long long E, int n) {
    int is64 = detect64(ei);
    long long e = (long long)blockIdx.x * blockDim.x + threadIdx.x;
    if (e >= E) return;
    int d = load_idx(ei, E, 1, e, is64);
    int r = -1;
    if ((unsigned)d < (unsigned)n) r = atomicAdd(&wcur[d], 1);
    posbuf[e] = r;
}

// ------------------------------------------------ 3-phase multi-block scan
__global__ __launch_bounds__(SCHUNK) void scan_p1_kernel(
        const int* __restrict__ deg, int* __restrict__ bsum, int n) {
    __shared__ int sd[SCHUNK];
    int b = blockIdx.x, t = threadIdx.x;
    int i = b * SCHUNK + t;
    sd[t] = (i < n) ? deg[i] : 0;
    __syncthreads();
    for (int off = SCHUNK / 2; off > 0; off >>= 1) {
        if (t < off) sd[t] += sd[t + off];
        __syncthreads();
    }
    if (t == 0) bsum[b] = sd[0];
}

__global__ __launch_bounds__(SCHUNK) void scan_p2_kernel(
        const int* __restrict__ bsum, int* __restrict__ boff, int nb,
        int* __restrict__ rowstart_n) {
    __shared__ int sd[SCHUNK];
    __shared__ int s_carry;
    int t = threadIdx.x;
    if (t == 0) s_carry = 0;
    __syncthreads();
    int nloop = (nb + SCHUNK - 1) / SCHUNK;
    for (int bi = 0; bi < nloop; ++bi) {
        int i = bi * SCHUNK + t;
        int v = (i < nb) ? bsum[i] : 0;
        sd[t] = v;
        __syncthreads();
        for (int off = 1; off < SCHUNK; off <<= 1) {
            int add = (t >= off) ? sd[t - off] : 0;
            __syncthreads();
            sd[t] += add;
            __syncthreads();
        }
        int carry = s_carry;
        if (i < nb) boff[i] = carry + sd[t] - v;
        __syncthreads();
        if (t == SCHUNK - 1) s_carry = carry + sd[SCHUNK - 1];
        __syncthreads();
    }
    if (t == 0) *rowstart_n = s_carry;  // rowstart[n] = total
}

__global__ __launch_bounds__(SCHUNK) void scan_p3_kernel(
        const int* __restrict__ deg, const int* __restrict__ boff,
        int* __restrict__ rowstart, float* __restrict__ dinv, int n) {
    __shared__ int sd[SCHUNK];
    int b = blockIdx.x, t = threadIdx.x;
    int i = b * SCHUNK + t;
    int v = (i < n) ? deg[i] : 0;
    sd[t] = v;
    __syncthreads();
    for (int off = 1; off < SCHUNK; off <<= 1) {
        int add = (t >= off) ? sd[t - off] : 0;
        __syncthreads();
        sd[t] += add;
        __syncthreads();
    }
    if (i < n) {
        rowstart[i] = boff[b] + sd[t] - v;
        dinv[i] = rsqrtf((float)(v + 1));
    }
}

// Pass B: pos = rowstart[d] + rank; no atomics. Every slot of every
// [rowstart[d], rowstart[d+1]) range is written exactly once per call with
// a validated s < n, so gather needs no per-edge guards.
__global__ __launch_bounds__(256) void scatter_elist_kernel(
        const void* ei, const int* __restrict__ posbuf,
        const int* __restrict__ rowstart, unsigned* __restrict__ selist,
        long long E, int n) {
    int is64 = detect64(ei);
    long long e = (long long)blockIdx.x * blockDim.x + threadIdx.x;
    if (e >= E) return;
    int r = posbuf[e];
    if (r < 0) return;
    int d = load_idx(ei, E, 1, e, is64);       // valid (r >= 0 implies it was)
    int s = load_idx(ei, E, 0, e, is64);
    if ((unsigned)s >= (unsigned)n) s = d;     // safe fallback
    long long pos = (long long)rowstart[d] + r;
    if (pos >= 0 && pos < E)
        selist[pos] = (unsigned)s << 7;        // byte offset into fp8 table
}

// ----------------------------------------------------- W f32 -> f16 convert
__global__ __launch_bounds__(256) void cvt_w_kernel(
        const float* __restrict__ W1, const float* __restrict__ W2,
        f16* __restrict__ W1h, f16* __restrict__ W2h) {
    int gid = blockIdx.x * blockDim.x + threadIdx.x;
    if (gid < 4096) {
        float4 v = ((const float4*)W1)[gid];
        ((f16x4*)W1h)[gid] = (f16x4){(f16)v.x, (f16)v.y, (f16)v.z, (f16)v.w};
    } else if (gid < 8192) {
        int g = gid - 4096;
        float4 v = ((const float4*)W2)[g];
        ((f16x4*)W2h)[g] = (f16x4){(f16)v.x, (f16)v.y, (f16)v.z, (f16)v.w};
    }
}

// -------------------------------------------------------------- MFMA GEMM
// Yq[r][c] = fp8( F8SCALE * dinv[r] * sum_k Xin[r][k] * Wh[k][c] )
template <bool F32IN>
__global__ __launch_bounds__(256) void gemm_mfma_kernel(
        const void* __restrict__ Xin, const f16* __restrict__ Wh,
        const float* __restrict__ dinv, unsigned char* __restrict__ Yq,
        int n) {
    __shared__ f16 wT[HDIM][HDIM + 8];  // wT[col][k], 272B row: 2-way banks
    int t = threadIdx.x;
    {   // stage W transposed: 2 threads per W row, 64 halves each
        int k = t >> 1, c0 = (t & 1) * 64;
        const f16x8* src = (const f16x8*)(Wh + (size_t)k * HDIM + c0);
#pragma unroll
        for (int j = 0; j < 8; ++j) {
            f16x8 v = src[j];
#pragma unroll
            for (int e = 0; e < 8; ++e) wT[c0 + j * 8 + e][k] = v[e];
        }
    }
    __syncthreads();
    int wid = t >> 6, lane = t & 63;
    int cl = lane & 15, kg = lane >> 4;
    int row0 = blockIdx.x * 64 + wid * 16;  // 16 rows per wave
    int rA = row0 + cl;
    bool okA = rA < n;
    f32x4 acc[8];
#pragma unroll
    for (int c = 0; c < 8; ++c) acc[c] = (f32x4){0.f, 0.f, 0.f, 0.f};
#pragma unroll
    for (int ks = 0; ks < 4; ++ks) {
        f16x8 a;
        if (okA) {
            if constexpr (F32IN) {
                const float* ap =
                    (const float*)Xin + (size_t)rA * HDIM + kg * 8 + ks * 32;
                float4 v0 = *(const float4*)ap;
                float4 v1 = *(const float4*)(ap + 4);
                a = (f16x8){(f16)v0.x, (f16)v0.y, (f16)v0.z, (f16)v0.w,
                            (f16)v1.x, (f16)v1.y, (f16)v1.z, (f16)v1.w};
            } else {
                const f16* ap =
                    (const f16*)Xin + (size_t)rA * HDIM + kg * 8 + ks * 32;
                a = *(const f16x8*)ap;
            }
        } else {
#pragma unroll
            for (int e = 0; e < 8; ++e) a[e] = (f16)0.f;
        }
#pragma unroll
        for (int c = 0; c < 8; ++c) {
            f16x8 b = *(const f16x8*)(&wT[c * 16 + cl][ks * 32 + kg * 8]);
            acc[c] = __builtin_amdgcn_mfma_f32_16x16x32_f16(a, b, acc[c], 0, 0, 0);
        }
    }
    int orow = row0 + kg * 4;
    float dv[4];
#pragma unroll
    for (int j = 0; j < 4; ++j)
        dv[j] = (orow + j < n) ? dinv[orow + j] * F8SCALE : 0.f;
#pragma unroll
    for (int c = 0; c < 8; ++c) {
#pragma unroll
        for (int j = 0; j < 4; ++j) {
            int gr = orow + j;
            if (gr < n) {
                float sv = acc[c][j] * dv[j];
                int w = __builtin_amdgcn_cvt_pk_fp8_f32(sv, sv, 0, false);
                Yq[(size_t)gr * HDIM + c * 16 + cl] = (unsigned char)(w & 0xff);
            }
        }
    }
}

// ---------------------------------------------------------- shared gather
// Aggregates self + fp8 neighbor msgs for node v; returns f32x2/lane
// (sum is F8SCALE-scaled). Scalar-pipe addressing: rowstart bounds forced
// into SGPRs via readfirstlane, so selist[] reads become s_load and each
// message load is global_load_ushort with SGPR base + uniform lane offset.
// Accumulation via f32x2 (v_pk_add_f32).
__device__ __forceinline__ f32x2 cvt_f8x2(unsigned short u) {
    return __builtin_amdgcn_cvt_pk_f32_fp8((int)u, false);
}

__device__ __forceinline__ f32x2 gather_node(
        const unsigned char* __restrict__ Yq, const int* __restrict__ rowstart,
        const unsigned* __restrict__ selist, int v, int lane) {
    unsigned loff = (unsigned)lane * 2u;
    f32x2 acc =
        cvt_f8x2(*(const unsigned short*)(Yq + ((unsigned)v << 7) + loff));
    f32x2 acc2 = (f32x2){0.f, 0.f};
    int i = __builtin_amdgcn_readfirstlane(rowstart[v]);
    int e = __builtin_amdgcn_readfirstlane(rowstart[v + 1]);
    for (; i + 8 <= e; i += 8) {
        const unsigned char* p0 = Yq + selist[i];      // SGPR base per edge
        const unsigned char* p1 = Yq + selist[i + 1];
        const unsigned char* p2 = Yq + selist[i + 2];
        const unsigned char* p3 = Yq + selist[i + 3];
        const unsigned char* p4 = Yq + selist[i + 4];
        const unsigned char* p5 = Yq + selist[i + 5];
        const unsigned char* p6 = Yq + selist[i + 6];
        const unsigned char* p7 = Yq + selist[i + 7];
        unsigned short m0 = *(const unsigned short*)(p0 + loff);
        unsigned short m1 = *(const unsigned short*)(p1 + loff);
        unsigned short m2 = *(const unsigned short*)(p2 + loff);
        unsigned short m3 = *(const unsigned short*)(p3 + loff);
        unsigned short m4 = *(const unsigned short*)(p4 + loff);
        unsigned short m5 = *(const unsigned short*)(p5 + loff);
        unsigned short m6 = *(const unsigned short*)(p6 + loff);
        unsigned short m7 = *(const unsigned short*)(p7 + loff);
        f32x2 f0 = cvt_f8x2(m0), f1 = cvt_f8x2(m1);
        f32x2 f2 = cvt_f8x2(m2), f3 = cvt_f8x2(m3);
        f32x2 f4 = cvt_f8x2(m4), f5 = cvt_f8x2(m5);
        f32x2 f6 = cvt_f8x2(m6), f7 = cvt_f8x2(m7);
        acc += (f0 + f1) + (f2 + f3);
        acc2 += (f4 + f5) + (f6 + f7);
    }
    for (; i < e; ++i) {
        const unsigned char* p = Yq + selist[i];
        acc += cvt_f8x2(*(const unsigned short*)(p + loff));
    }
    return acc + acc2;
}

// -------------------------------------------------------------------- pull
// Bh[v] = fp16( relu(bias + dinv[v]/F8SCALE * gathered) )      (layer 1)
__global__ __launch_bounds__(256) void pull_relu_kernel(
        const unsigned char* __restrict__ Yq, const int* __restrict__ rowstart,
        const unsigned* __restrict__ selist, const float* __restrict__ dinv,
        const float* __restrict__ bias, __half* __restrict__ Bh, int n) {
    int v = (int)((blockIdx.x * blockDim.x + threadIdx.x) >> 6);
    int lane = threadIdx.x & 63;
    if (v >= n) return;
    f32x2 a = gather_node(Yq, rowstart, selist, v, lane);
    float dv = dinv[v] * F8INV;
    float2 b = ((const float2*)bias)[lane];
    float hx = fmaxf(fmaf(dv, a.x, b.x), 0.f);
    float hy = fmaxf(fmaf(dv, a.y, b.y), 0.f);
    ((__half2*)(Bh + (size_t)v * HDIM))[lane] = __floats2half2_rn(hx, hy);
}

// ------------------------------------------- fused pull (layer 2) + heads
#define SENT (-3.0e38f)
#define BFLY(p) \
    p += __shfl_xor(p, 32); p += __shfl_xor(p, 16); p += __shfl_xor(p, 8); \
    p += __shfl_xor(p, 4);  p += __shfl_xor(p, 2);  p += __shfl_xor(p, 1);

__global__ __launch_bounds__(256) void pull_heads_kernel(
        const unsigned char* __restrict__ Yq, const int* __restrict__ rowstart,
        const unsigned* __restrict__ selist, const float* __restrict__ dinv,
        const float* __restrict__ bias,
        const float* __restrict__ Wdet, const float* __restrict__ bdet,
        const float* __restrict__ Wund, const float* __restrict__ bund,
        const float* __restrict__ Wroot, const float* __restrict__ broot,
        float* __restrict__ out, int n) {
    int v = (int)((blockIdx.x * blockDim.x + threadIdx.x) >> 6);
    int lane = threadIdx.x & 63;
    if (v >= n) return;
    f32x2 a = gather_node(Yq, rowstart, selist, v, lane);
    float dv = dinv[v] * F8INV;
    float2 b = ((const float2*)bias)[lane];
    float hx = fmaxf(fmaf(dv, a.x, b.x), 0.f);   // h[2*lane]
    float hy = fmaxf(fmaf(dv, a.y, b.y), 0.f);   // h[2*lane+1]

    float4 wd  = ((const float4*)Wdet)[lane];
    float4 wu  = ((const float4*)Wund)[lane];
    float4 wr0 = ((const float4*)Wroot)[2 * lane];
    float4 wr1 = ((const float4*)Wroot)[2 * lane + 1];
    float pd0 = hx * wd.x + hy * wd.z;
    float pd1 = hx * wd.y + hy * wd.w;
    float pu0 = hx * wu.x + hy * wu.z;
    float pu1 = hx * wu.y + hy * wu.w;
    float pr0 = hx * wr0.x + hy * wr1.x;
    float pr1 = hx * wr0.y + hy * wr1.y;
    float pr2 = hx * wr0.z + hy * wr1.z;
    float pr3 = hx * wr0.w + hy * wr1.w;
    BFLY(pd0); BFLY(pd1); BFLY(pu0); BFLY(pu1);
    BFLY(pr0); BFLY(pr1); BFLY(pr2); BFLY(pr3);

    if (lane == 0) {
        float d0 = pd0 + bdet[0], d1 = pd1 + bdet[1];
        float u0 = pu0 + bund[0], u1 = pu1 + bund[1];
        float r0 = pr0 + broot[0], r1 = pr1 + broot[1];
        float r2 = pr2 + broot[2], r3 = pr3 + broot[3];
        float m = fmaxf(d0, d1);
        float lse = m + logf(expf(d0 - m) + expf(d1 - m));
        out[(size_t)v * 2 + 0] = fin(d0 - lse);
        out[(size_t)v * 2 + 1] = fin(d1 - lse);
        float* ro = out + 2 * (size_t)n + (size_t)v * 5;
        if (d1 > d0) {  // argmax == 1 (tie -> index 0 -> false)
            float mm = fmaxf(fmaxf(r0, r1), fmaxf(r2, r3));
            float l2 = mm + logf(expf(r0 - mm) + expf(r1 - mm) +
                                 expf(r2 - mm) + expf(r3 - mm));
            ro[0] = SENT;  // reference: -inf (finite sentinel, inf-inf=nan)
            ro[1] = fin(r0 - l2);
            ro[2] = fin(r1 - l2);
            ro[3] = fin(r2 - l2);
            ro[4] = fin(r3 - l2);
        } else {
            float mm = fmaxf(u0, u1);
            float l2 = mm + logf(expf(u0 - mm) + expf(u1 - mm));
            ro[0] = fin(u0 - l2);
            ro[1] = fin(u1 - l2);
            ro[2] = SENT;
            ro[3] = SENT;
            ro[4] = SENT;
        }
    }
}

__global__ void ws_too_small_kernel(float* out, int n) {
    int i = blockIdx.x * blockDim.x + threadIdx.x;
    if (i < n) out[i] = -12345.0f;  // sentinel: workspace was insufficient
}

// ----------------------------------------------------------------- launch
extern "C" void kernel_launch(void* const* d_in, const int* in_sizes, int n_in,
                              void* d_out, int out_size, void* d_ws,
                              size_t ws_size, hipStream_t stream) {
    const float* x     = (const float*)d_in[0];
    const void*  ei    = d_in[1];
    const float* W1    = (const float*)d_in[2];
    const float* b1    = (const float*)d_in[3];
    const float* W2    = (const float*)d_in[4];
    const float* b2    = (const float*)d_in[5];
    const float* Wdet  = (const float*)d_in[6];
    const float* bdet  = (const float*)d_in[7];
    const float* Wund  = (const float*)d_in[8];
    const float* bund  = (const float*)d_in[9];
    const float* Wroot = (const float*)d_in[10];
    const float* broot = (const float*)d_in[11];
    int N = in_sizes[0] / HDIM;       // 50000
    long long E = in_sizes[1] / 2;    // 800000
    float* out = (float*)d_out;
    int nb = (N + SCHUNK - 1) / SCHUNK;

    // workspace carve (256B aligned)
    size_t off = 0;
    auto carve = [&](size_t bytes) -> void* {
        void* p = (char*)d_ws + off;
        off += (bytes + 255) & ~(size_t)255;
        return p;
    };
    unsigned char* Yq   = (unsigned char*)carve((size_t)N * HDIM);
    __half*   Bh       = (__half*)carve((size_t)N * HDIM * 2);
    f16*      W1h      = (f16*)carve((size_t)HDIM * HDIM * 2);
    f16*      W2h      = (f16*)carve((size_t)HDIM * HDIM * 2);
    float*    dinv     = (float*)carve((size_t)N * 4);
    int*      rowstart = (int*)carve((size_t)(N + 1) * 4);
    int*      wcur     = (int*)carve((size_t)N * 4);
    int*      posbuf   = (int*)carve((size_t)E * 4);
    unsigned* selist   = (unsigned*)carve((size_t)E * 4);
    int*      bsum     = (int*)carve((size_t)nb * 4);
    int*      boff     = (int*)carve((size_t)nb * 4);

    if (off > ws_size) {
        ws_too_small_kernel<<<(out_size + 255) / 256, 256, 0, stream>>>(out, out_size);
        return;
    }

    int e1grid = (int)((E + 255) / 256);

    // CSR build (2 edge passes)
    zero_cnt_kernel<<<256, 256, 0, stream>>>(wcur, N);
    pos_edges_kernel<<<e1grid, 256, 0, stream>>>(ei, wcur, posbuf, E, N);
    scan_p1_kernel<<<nb, SCHUNK, 0, stream>>>(wcur, bsum, N);
    scan_p2_kernel<<<1, SCHUNK, 0, stream>>>(bsum, boff, nb, rowstart + N);
    scan_p3_kernel<<<nb, SCHUNK, 0, stream>>>(wcur, boff, rowstart, dinv, N);
    scatter_elist_kernel<<<e1grid, 256, 0, stream>>>(ei, posbuf, rowstart,
                                                     selist, E, N);
    // W conversions
    cvt_w_kernel<<<32, 256, 0, stream>>>(W1, W2, W1h, W2h);

    int gemm_grid = (N + 63) / 64;
    int pull_grid = (N + 3) / 4;      // 4 waves (nodes) per 256-thread block

    // layer 1: Yq = fp8(16*dinv*(x @ W1));  Bh = fp16(relu(b1 + dinv*(...)))
    gemm_mfma_kernel<true><<<gemm_grid, 256, 0, stream>>>(x, W1h, dinv, Yq, N);
    pull_relu_kernel<<<pull_grid, 256, 0, stream>>>(Yq, rowstart, selist,
                                                    dinv, b1, Bh, N);
    // layer 2: Yq = fp8(16*dinv*(Bh @ W2)); fused pull + heads -> out
    gemm_mfma_kernel<false><<<gemm_grid, 256, 0, stream>>>(Bh, W2h, dinv, Yq, N);
    pull_heads_kernel<<<pull_grid, 256, 0, stream>>>(Yq, rowstart, selist,
                                                     dinv, b2, Wdet, bdet,
                                                     Wund, bund, Wroot, broot,
                                                     out, N);
}